// Round 2
// baseline (1484.372 us; speedup 1.0000x reference)
//
#include <hip/hip_runtime.h>

#define N_NODES 100000
#define M_PAD   100096   // 782 * 128
#define N_MBLK  782
#define N_EDGES 1600000
#define N_GRAPHS 64
#define HID 256
#define PROJ 128
#define NLAYERS 4

#define EBUF_STRIDE 8192
#define N_BUCKETS ((N_NODES + 255) / 256)  // 391

typedef unsigned short u16;
typedef __attribute__((ext_vector_type(8))) short bf16x8;
typedef __attribute__((ext_vector_type(4))) float f32x4;
typedef __attribute__((ext_vector_type(2))) float vf2;

__device__ __forceinline__ float b2f(u16 u) {
  return __uint_as_float(((unsigned)u) << 16);
}
__device__ __forceinline__ float b2f_lo(unsigned u) {
  return __uint_as_float(u << 16);
}
__device__ __forceinline__ float b2f_hi(unsigned u) {
  return __uint_as_float(u & 0xFFFF0000u);
}
__device__ __forceinline__ u16 f2b(float f) {
  unsigned u = __float_as_uint(f);
  u = (u + 0x7FFF + ((u >> 16) & 1)) >> 16;  // round-to-nearest-even
  return (u16)u;
}
__device__ __forceinline__ void gload16(const void* g, void* l) {
  __builtin_amdgcn_global_load_lds((const __attribute__((address_space(1))) void*)g,
                                   (__attribute__((address_space(3))) void*)l, 16, 0, 0);
}
// ---- fp8 e4m3 (HW cvt; encode/decode self-consistent) ----
__device__ __forceinline__ unsigned pack_fp8x4(float a, float b, float c, float d) {
  int v = __builtin_amdgcn_cvt_pk_fp8_f32(a, b, 0, false);
  v = __builtin_amdgcn_cvt_pk_fp8_f32(c, d, v, true);
  return (unsigned)v;
}
__device__ __forceinline__ void accf8(float* a, unsigned w) {
  vf2 lo = __builtin_amdgcn_cvt_pk_f32_fp8((int)w, false);
  vf2 hi = __builtin_amdgcn_cvt_pk_f32_fp8((int)w, true);
  a[0] += lo.x; a[1] += lo.y; a[2] += hi.x; a[3] += hi.y;
}

// ---------------------------------------------------------------- CSR -------
// Pass A: fused degree count + coarse bucket scatter (bucket = dst>>8).
// Appends hit only N_BUCKETS tail lines -> ~1x write amplification, vs the
// old direct scatter's 16x (107 MB for a 6.4 MB buffer).
__global__ void bucket_count_scatter(const int* __restrict__ src,
                                     const int* __restrict__ dst,
                                     int* __restrict__ cnt,
                                     int* __restrict__ bfill,
                                     uint2* __restrict__ ebuf) {
  int e = blockIdx.x * blockDim.x + threadIdx.x;
  if (e < N_EDGES) {
    int d = dst[e];
    int s = src[e];
    atomicAdd(&cnt[d], 1);
    int b = d >> 8;
    int p = atomicAdd(&bfill[b], 1);
    if (p < EBUF_STRIDE) {  // 64-sigma margin; drop-safe guard
      uint2 q; q.x = (unsigned)s; q.y = (unsigned)d;
      ebuf[(size_t)b * EBUF_STRIDE + p] = q;
    }
  }
}

__global__ void inv_kernel(const int* __restrict__ cnt, float* __restrict__ inv) {
  int n = blockIdx.x * blockDim.x + threadIdx.x;
  if (n < N_NODES) inv[n] = 1.0f / fmaxf((float)cnt[n], 1.0f);
}

#define SCAN_BLK 1024
#define N_SCAN_BLOCKS ((N_NODES + SCAN_BLK - 1) / SCAN_BLK)  // 98

__global__ __launch_bounds__(256) void scan_partial(const int* __restrict__ cnt,
                                                    int* __restrict__ bsum) {
  __shared__ int red[256];
  int t = threadIdx.x;
  int base = blockIdx.x * SCAN_BLK + t * 4;
  int s = 0;
#pragma unroll
  for (int j = 0; j < 4; j++) {
    int i = base + j;
    if (i < N_NODES) s += cnt[i];
  }
  red[t] = s;
  __syncthreads();
  for (int off = 128; off > 0; off >>= 1) {
    if (t < off) red[t] += red[t + off];
    __syncthreads();
  }
  if (t == 0) bsum[blockIdx.x] = red[0];
}

__global__ __launch_bounds__(128) void scan_bsums(const int* __restrict__ bsum,
                                                  int* __restrict__ boff) {
  __shared__ int tile[128];
  int t = threadIdx.x;
  int v = (t < N_SCAN_BLOCKS) ? bsum[t] : 0;
  tile[t] = v;
  __syncthreads();
#pragma unroll
  for (int off = 1; off < 128; off <<= 1) {
    int add = (t >= off) ? tile[t - off] : 0;
    __syncthreads();
    tile[t] += add;
    __syncthreads();
  }
  if (t < N_SCAN_BLOCKS) boff[t] = tile[t] - v;  // exclusive
}

__global__ __launch_bounds__(256) void scan_final(const int* __restrict__ cnt,
                                                  const int* __restrict__ boff,
                                                  int* __restrict__ row_ptr) {
  __shared__ int tsum[256];
  int t = threadIdx.x;
  int base = blockIdx.x * SCAN_BLK + t * 4;
  int v[4];
  int s = 0;
#pragma unroll
  for (int j = 0; j < 4; j++) {
    int i = base + j;
    v[j] = (i < N_NODES) ? cnt[i] : 0;
    s += v[j];
  }
  tsum[t] = s;
  __syncthreads();
#pragma unroll
  for (int off = 1; off < 256; off <<= 1) {
    int add = (t >= off) ? tsum[t - off] : 0;
    __syncthreads();
    tsum[t] += add;
    __syncthreads();
  }
  int excl = tsum[t] - s + boff[blockIdx.x];
#pragma unroll
  for (int j = 0; j < 4; j++) {
    int i = base + j;
    if (i < N_NODES) {
      row_ptr[i] = excl;
      excl += v[j];
    }
  }
  if (blockIdx.x == 0 && t == 0) row_ptr[N_NODES] = N_EDGES;
}

// Pass B: sweep bucket slots; a block's edges share one bucket (256-node dst
// range) so col writes land in a ~16 KB window that stays L2-resident.
__global__ void fill_from_ebuf(const uint2* __restrict__ ebuf,
                               const int* __restrict__ bfill,
                               const int* __restrict__ row_ptr,
                               int* __restrict__ fill,
                               int* __restrict__ col) {
  int idx = blockIdx.x * blockDim.x + threadIdx.x;
  int b = idx >> 13;                 // / EBUF_STRIDE
  int sl = idx & (EBUF_STRIDE - 1);
  if (b < N_BUCKETS && sl < bfill[b]) {
    uint2 q = ebuf[(size_t)b * EBUF_STRIDE + sl];
    int d = (int)q.y;
    int pos = row_ptr[d] + atomicAdd(&fill[d], 1);
    col[pos] = (int)q.x;
  }
}

// ------------------------------------------------------------ converts ------
__global__ __launch_bounds__(256) void convert_x(const float4* __restrict__ x,
                                                 ushort4* __restrict__ hb,
                                                 unsigned* __restrict__ h8) {
  int i = blockIdx.x * blockDim.x + threadIdx.x;  // exactly N_NODES*64 threads
  float4 v = x[i];
  ushort4 o;
  o.x = f2b(v.x); o.y = f2b(v.y); o.z = f2b(v.z); o.w = f2b(v.w);
  hb[i] = o;
  h8[i] = pack_fp8x4(v.x, v.y, v.z, v.w);
}

// Wt[l][n][k] bf16, k<256 -> Wl[l][k][n], k>=256 -> Wr[l][k-256][n]
__global__ __launch_bounds__(256) void convert_w(const float* __restrict__ Wl,
                                                 const float* __restrict__ Wr,
                                                 u16* __restrict__ Wt) {
  int idx = blockIdx.x * blockDim.x + threadIdx.x;  // 4*256*512 threads
  int l = idx >> 17;
  int r = idx & ((1 << 17) - 1);
  int n = r >> 9;
  int k = r & 511;
  float v = (k < 256) ? Wl[(size_t)l * 65536 + k * 256 + n]
                      : Wr[(size_t)l * 65536 + (k - 256) * 256 + n];
  Wt[idx] = f2b(v);
}

// ----------------------------------------------------------- aggregation ----
// one wave per node; two 32-lane halves process alternating edges with 8B fp8
// loads (full 256B row per half); up to 8 gathers in flight per half.
__global__ __launch_bounds__(256) void aggregate_fp8(
    const unsigned char* __restrict__ h8, const int* __restrict__ row_ptr,
    const int* __restrict__ col, const float* __restrict__ inv_cnt,
    u16* __restrict__ aggr) {
  int node = blockIdx.x * 4 + (threadIdx.x >> 6);
  int lane = threadIdx.x & 63;
  int half = lane >> 5, l32 = lane & 31;
  int r0 = row_ptr[node], r1 = row_ptr[node + 1];
  float a[8] = {0.f, 0.f, 0.f, 0.f, 0.f, 0.f, 0.f, 0.f};
  int e = r0 + half;
  for (; e + 14 < r1; e += 16) {
    int s[8];
#pragma unroll
    for (int j = 0; j < 8; j++) s[j] = col[e + 2 * j];
    uint2 v[8];
#pragma unroll
    for (int j = 0; j < 8; j++)
      v[j] = *((const uint2*)(h8 + (size_t)s[j] * HID) + l32);
#pragma unroll
    for (int j = 0; j < 8; j++) { accf8(a, v[j].x); accf8(a + 4, v[j].y); }
  }
  for (; e + 6 < r1; e += 8) {
    int s0 = col[e], s1 = col[e + 2], s2 = col[e + 4], s3 = col[e + 6];
    uint2 v0 = *((const uint2*)(h8 + (size_t)s0 * HID) + l32);
    uint2 v1 = *((const uint2*)(h8 + (size_t)s1 * HID) + l32);
    uint2 v2 = *((const uint2*)(h8 + (size_t)s2 * HID) + l32);
    uint2 v3 = *((const uint2*)(h8 + (size_t)s3 * HID) + l32);
    accf8(a, v0.x); accf8(a + 4, v0.y);
    accf8(a, v1.x); accf8(a + 4, v1.y);
    accf8(a, v2.x); accf8(a + 4, v2.y);
    accf8(a, v3.x); accf8(a + 4, v3.y);
  }
  for (; e < r1; e += 2) {
    int s0 = col[e];
    uint2 v0 = *((const uint2*)(h8 + (size_t)s0 * HID) + l32);
    accf8(a, v0.x); accf8(a + 4, v0.y);
  }
#pragma unroll
  for (int j = 0; j < 8; j++) a[j] += __shfl_xor(a[j], 32, 64);
  if (half == 0) {
    float inv = inv_cnt[node];
    uint4 o;
    o.x = (unsigned)f2b(a[0] * inv) | ((unsigned)f2b(a[1] * inv) << 16);
    o.y = (unsigned)f2b(a[2] * inv) | ((unsigned)f2b(a[3] * inv) << 16);
    o.z = (unsigned)f2b(a[4] * inv) | ((unsigned)f2b(a[5] * inv) << 16);
    o.w = (unsigned)f2b(a[6] * inv) | ((unsigned)f2b(a[7] * inv) << 16);
    *((uint4*)(aggr + (size_t)node * HID) + l32) = o;
  }
}

// ------------------------------------- MFMA GEMM + fused BN partials --------
// hpre[m][n] = sum_k cat(aggr,h)[m][k] * B[k][n];  B^T given as Wt[n][k].
// 128x256 tile, BK=32, 4 waves each 64x128.  hpre may alias hb (in-place):
// each block reads A rows [m0,m0+128) and writes C to exactly those rows,
// with all A reads completing (vmcnt-drained syncthreads) before the C store.
__global__ __launch_bounds__(256, 2) void gemm_fused(
    const u16* hb, const u16* __restrict__ aggr,
    const u16* __restrict__ Bt, u16* hpre,
    float* __restrict__ psum) {
  __shared__ u16 smem[128 * 32 + 256 * 32];  // 24 KB: staging; reused as epilogue buf
  __shared__ float bns[4][8][16][2];         // 4 KB
  u16* As = smem;
  u16* Bs = smem + 128 * 32;
  u16* ep = smem;  // 32 rows x 256 cols bf16 = 16 KB (used after final K-loop sync)

  int tid = threadIdx.x;
  int wid = tid >> 6, lane = tid & 63;
  int m0 = blockIdx.x * 128;
  int q = lane >> 4, c = lane & 15;
  int wm = (wid >> 1) * 64, wn = (wid & 1) * 128;

  f32x4 zero = {0.f, 0.f, 0.f, 0.f};
  f32x4 acc[4][8];
#pragma unroll
  for (int mi = 0; mi < 4; mi++)
#pragma unroll
    for (int ni = 0; ni < 8; ni++) acc[mi][ni] = zero;

  // A staging geometry (2 issues/thread)
  int srowA0 = wid * 32 + (lane >> 2);
  int cgA0 = (lane & 3) ^ ((srowA0 >> 1) & 3);
  int srowA1 = srowA0 + 16;
  int cgA1 = (lane & 3) ^ ((srowA1 >> 1) & 3);
  // B staging geometry (4 issues/thread)
  int srowB[4], cgB[4];
#pragma unroll
  for (int j = 0; j < 4; j++) {
    srowB[j] = j * 64 + wid * 16 + (lane >> 2);
    cgB[j] = (lane & 3) ^ ((srowB[j] >> 1) & 3);
  }

  // frag-read LDS offsets (elements), loop-invariant
  int aoff[4], boff[8];
#pragma unroll
  for (int mi = 0; mi < 4; mi++) {
    int row = wm + mi * 16 + c;
    aoff[mi] = row * 32 + ((q ^ ((row >> 1) & 3)) << 3);
  }
#pragma unroll
  for (int ni = 0; ni < 8; ni++) {
    int row = wn + ni * 16 + c;
    boff[ni] = row * 32 + ((q ^ ((row >> 1) & 3)) << 3);
  }

  for (int k0 = 0; k0 < 512; k0 += 32) {
    const u16* Asrc = (k0 < 256) ? aggr : hb;
    int ksrc = k0 & 255;
    gload16(Asrc + ((size_t)(m0 + srowA0) * HID + ksrc + cgA0 * 8), &As[(wid * 32) * 32]);
    gload16(Asrc + ((size_t)(m0 + srowA1) * HID + ksrc + cgA1 * 8), &As[(wid * 32 + 16) * 32]);
#pragma unroll
    for (int j = 0; j < 4; j++)
      gload16(Bt + ((size_t)srowB[j] * 512 + k0 + cgB[j] * 8), &Bs[(j * 64 + wid * 16) * 32]);
    __syncthreads();
    bf16x8 af[4], bfr[8];
#pragma unroll
    for (int mi = 0; mi < 4; mi++) af[mi] = *(const bf16x8*)&As[aoff[mi]];
#pragma unroll
    for (int ni = 0; ni < 8; ni++) bfr[ni] = *(const bf16x8*)&Bs[boff[ni]];
#pragma unroll
    for (int mi = 0; mi < 4; mi++)
#pragma unroll
      for (int ni = 0; ni < 8; ni++)
        acc[mi][ni] = __builtin_amdgcn_mfma_f32_16x16x32_bf16(af[mi], bfr[ni],
                                                              acc[mi][ni], 0, 0, 0);
    __syncthreads();
  }

  // ---- coalesced C-store: 4 slabs of 32 rows via LDS transpose ----
  int rh = wid >> 1;  // row half (0: rows 0-63, 1: rows 64-127)
#pragma unroll
  for (int mi = 0; mi < 4; mi++) {
#pragma unroll
    for (int r = 0; r < 4; r++) {
      int r16 = q * 4 + r;
#pragma unroll
      for (int ni = 0; ni < 8; ni++)
        ep[(rh * 16 + r16) * 256 + wn + ni * 16 + c] = f2b(acc[mi][ni][r]);
    }
    __syncthreads();
    int u = tid;
#pragma unroll
    for (int j = 0; j < 4; j++, u += 256) {
      int lr = u >> 5;     // 0..31 local row
      int cu = u & 31;     // uint4 column
      int gm = m0 + (lr >> 4) * 64 + mi * 16 + (lr & 15);
      if (gm < N_NODES)
        ((uint4*)(hpre + (size_t)gm * HID))[cu] = ((const uint4*)ep)[u];
    }
    __syncthreads();
  }

  // ---- BN column partials from fp32 acc (mask pad rows) ----
#pragma unroll
  for (int ni = 0; ni < 8; ni++) {
    float s = 0.f, s2 = 0.f;
#pragma unroll
    for (int mi = 0; mi < 4; mi++) {
#pragma unroll
      for (int r = 0; r < 4; r++) {
        int gm = m0 + wm + mi * 16 + q * 4 + r;
        float v = (gm < N_NODES) ? acc[mi][ni][r] : 0.f;
        s += v;
        s2 += v * v;
      }
    }
    s += __shfl_xor(s, 16, 64);
    s += __shfl_xor(s, 32, 64);
    s2 += __shfl_xor(s2, 16, 64);
    s2 += __shfl_xor(s2, 32, 64);
    if (q == 0) {
      bns[wid][ni][c][0] = s;
      bns[wid][ni][c][1] = s2;
    }
  }
  __syncthreads();
  {
    int wnh = tid >> 7, ni = (tid >> 4) & 7, cc = tid & 15;
    float s = bns[wnh][ni][cc][0] + bns[wnh + 2][ni][cc][0];
    float s2 = bns[wnh][ni][cc][1] + bns[wnh + 2][ni][cc][1];
    int coln = wnh * 128 + ni * 16 + cc;
    psum[(size_t)blockIdx.x * 512 + coln] = s;
    psum[(size_t)blockIdx.x * 512 + 256 + coln] = s2;
  }
}

// --------------------------------- BN reduce (tree, atomic-free) ------------
#define BN_MID 16
__global__ __launch_bounds__(256) void bn_mid(const float* __restrict__ psum,
                                              float* __restrict__ tmp) {
  int b = blockIdx.x;
  int f = threadIdx.x;
  int mb0 = b * 49;
  int mb1 = min(mb0 + 49, N_MBLK);
  float s = 0.f, s2 = 0.f;
  for (int mb = mb0; mb < mb1; mb++) {
    s += psum[(size_t)mb * 512 + f];
    s2 += psum[(size_t)mb * 512 + 256 + f];
  }
  tmp[(size_t)b * 512 + f] = s;
  tmp[(size_t)b * 512 + 256 + f] = s2;
}

__global__ void bn_fin(const float* __restrict__ tmp,
                       const float* __restrict__ gamma,
                       const float* __restrict__ beta,
                       float* __restrict__ ss) {
  int f = threadIdx.x;
  float sum = 0.f, sq = 0.f;
#pragma unroll
  for (int b = 0; b < BN_MID; b++) {
    sum += tmp[(size_t)b * 512 + f];
    sq += tmp[(size_t)b * 512 + 256 + f];
  }
  const float invN = 1.0f / (float)N_NODES;
  float mu = sum * invN;
  float ex2 = sq * invN;
  float var = fmaxf(ex2 - mu * mu, 0.f);
  float sc = gamma[f] * rsqrtf(var + 1e-5f);
  ss[f] = sc;
  ss[HID + f] = beta[f] - mu * sc;
}

// BN+ReLU apply, in-place on the bf16 h buffer, plus fp8 shadow copy for the
// next layer's aggregation gather.
__global__ __launch_bounds__(256) void bn_apply_fused(const uint4* hpre,
                                                      const float* __restrict__ ss,
                                                      uint4* hout,
                                                      uint2* __restrict__ h8out) {
  int idx0 = blockIdx.x * blockDim.x + threadIdx.x;
  int cb = (idx0 & 31) * 8;  // column base (row = 32 uint4)
  float sc[8], sh[8];
#pragma unroll
  for (int j = 0; j < 8; j++) { sc[j] = ss[cb + j]; sh[j] = ss[HID + cb + j]; }
  const int total = N_NODES * 32;
  const int step = gridDim.x * blockDim.x;  // 524288, multiple of 32
  for (int i = idx0; i < total; i += step) {
    uint4 v = hpre[i];
    unsigned vv[4] = {v.x, v.y, v.z, v.w};
    unsigned o[4];
    float f[8];
#pragma unroll
    for (int j = 0; j < 4; j++) {
      float lo = fmaxf(fmaf(b2f_lo(vv[j]), sc[2 * j], sh[2 * j]), 0.f);
      float hi = fmaxf(fmaf(b2f_hi(vv[j]), sc[2 * j + 1], sh[2 * j + 1]), 0.f);
      f[2 * j] = lo;
      f[2 * j + 1] = hi;
      o[j] = (unsigned)f2b(lo) | ((unsigned)f2b(hi) << 16);
    }
    uint4 ov = {o[0], o[1], o[2], o[3]};
    hout[i] = ov;
    uint2 q;
    q.x = pack_fp8x4(f[0], f[1], f[2], f[3]);
    q.y = pack_fp8x4(f[4], f[5], f[6], f[7]);
    h8out[i] = q;
  }
}

// ---------------- pool stage 1: per-(graph, chunk) BN+ReLU partial sums -----
// grid (64, 8); each block covers 1/8 of its graph's rows; atomic-free.
__global__ __launch_bounds__(256) void pool_partial(
    const u16* __restrict__ hpre, const float* __restrict__ ss,
    const int* __restrict__ batch, float* __restrict__ partial) {
  __shared__ float red[256][9];
  int g = blockIdx.x;
  int i = blockIdx.y;
  int t = threadIdx.x;
  // row range of graph g in sorted batch: [lo, hi)
  int a = 0, b = N_NODES;
  while (a < b) { int m = (a + b) >> 1; if (batch[m] < g) a = m + 1; else b = m; }
  int lo = a;
  b = N_NODES;
  while (a < b) { int m = (a + b) >> 1; if (batch[m] < g + 1) a = m + 1; else b = m; }
  int hi = a;
  int len = hi - lo;
  int clen = (len + 7) >> 3;
  int c0 = lo + i * clen;
  int c1 = min(c0 + clen, hi);

  int rs = t >> 5, cu = t & 31;
  int cb = cu * 8;
  float scv[8], shv[8];
#pragma unroll
  for (int j = 0; j < 8; j++) { scv[j] = ss[cb + j]; shv[j] = ss[HID + cb + j]; }
  float acc[8] = {0.f, 0.f, 0.f, 0.f, 0.f, 0.f, 0.f, 0.f};
  for (int r = c0 + rs; r < c1; r += 8) {
    uint4 v = *((const uint4*)(hpre + (size_t)r * HID) + cu);
    unsigned vv[4] = {v.x, v.y, v.z, v.w};
#pragma unroll
    for (int j = 0; j < 4; j++) {
      acc[2 * j]     += fmaxf(fmaf(b2f_lo(vv[j]), scv[2 * j], shv[2 * j]), 0.f);
      acc[2 * j + 1] += fmaxf(fmaf(b2f_hi(vv[j]), scv[2 * j + 1], shv[2 * j + 1]), 0.f);
    }
  }
#pragma unroll
  for (int j = 0; j < 8; j++) red[t][j] = acc[j];
  __syncthreads();
  // thread t reduces column t across the 8 row-strips
  int cc = t >> 3, j = t & 7;
  float sum = 0.f;
#pragma unroll
  for (int k = 0; k < 8; k++) sum += red[k * 32 + cc][j];
  partial[((size_t)g * 8 + i) * 256 + t] = sum;
}

// ---------------- pool stage 2 + MLP (64 blocks, reads 8 partials/graph) ----
__global__ __launch_bounds__(256) void pool_mlp_final(
    const float* __restrict__ partial, const int* __restrict__ batch,
    const float* __restrict__ W1, const float* __restrict__ b1,
    const float* __restrict__ W2, const float* __restrict__ b2,
    float* __restrict__ out) {
  __shared__ float gs[HID];
  __shared__ float ts[HID];
  __shared__ float rn[PROJ];
  int g = blockIdx.x;
  int t = threadIdx.x;
  // graph length via binary search
  int a = 0, b = N_NODES;
  while (a < b) { int m = (a + b) >> 1; if (batch[m] < g) a = m + 1; else b = m; }
  int lo = a;
  b = N_NODES;
  while (a < b) { int m = (a + b) >> 1; if (batch[m] < g + 1) a = m + 1; else b = m; }
  int len = a - lo;

  float sum = 0.f;
#pragma unroll
  for (int i = 0; i < 8; i++) sum += partial[((size_t)g * 8 + i) * 256 + t];
  float inv = 1.0f / fmaxf((float)len, 1.0f);
  gs[t] = sum * inv;
  __syncthreads();

  float s = b1[t];
  for (int k = 0; k < HID; k++) s = fmaf(gs[k], W1[(size_t)k * HID + t], s);
  ts[t] = fmaxf(s, 0.f);
  __syncthreads();
  float z = 0.f;
  if (t < PROJ) {
    z = b2[t];
    for (int k = 0; k < HID; k++) z = fmaf(ts[k], W2[(size_t)k * PROJ + t], z);
    rn[t] = z * z;
  }
  __syncthreads();
  for (int off = PROJ / 2; off > 0; off >>= 1) {
    if (t < off) rn[t] += rn[t + off];
    __syncthreads();
  }
  float norm = fmaxf(sqrtf(rn[0]), 1e-12f);
  if (t < PROJ) out[(size_t)g * PROJ + t] = z / norm;
}

// --------------------------------------------------------------- launch -----
extern "C" void kernel_launch(void* const* d_in, const int* in_sizes, int n_in,
                              void* d_out, int out_size, void* d_ws, size_t ws_size,
                              hipStream_t stream) {
  const float* x = (const float*)d_in[0];
  const int* ei = (const int*)d_in[1];
  const int* src = ei;
  const int* dst = ei + N_EDGES;
  const int* batch = (const int*)d_in[2];
  const float* Wl = (const float*)d_in[3];
  // d_in[4] = bl: per-column bias is exactly cancelled by BatchNorm -> unused
  const float* Wr = (const float*)d_in[5];
  const float* gamma = (const float*)d_in[6];
  const float* beta = (const float*)d_in[7];
  const float* W1 = (const float*)d_in[8];
  const float* b1 = (const float*)d_in[9];
  const float* W2 = (const float*)d_in[10];
  const float* b2 = (const float*)d_in[11];
  float* out = (float*)d_out;

  char* p = (char*)d_ws;
  const size_t HB = (size_t)M_PAD * HID * sizeof(u16);  // 51.25 MB
  u16* h = (u16*)p;      p += HB;                        // bf16 h / hpre (in-place)
  u16* aggr = (u16*)p;   p += HB;
  unsigned char* h8 = (unsigned char*)p; p += (size_t)M_PAD * HID;  // 25.6 MB fp8
  u16* Wt = (u16*)p;     p += (size_t)NLAYERS * 512 * HID * sizeof(u16);  // 1 MB
  int* col = (int*)p;    p += (size_t)N_EDGES * sizeof(int);              // 6.4 MB
  int* row_ptr = (int*)p; p += 400016;
  float* inv_cnt = (float*)p; p += (size_t)N_NODES * sizeof(float);
  float* psum = (float*)p;    p += (size_t)N_MBLK * 512 * sizeof(float);  // 1.6 MB
  float* tmp = (float*)p;     p += (size_t)BN_MID * 512 * sizeof(float);
  float* ss = (float*)p;      p += 512 * sizeof(float);
  float* partial = (float*)p; p += (size_t)N_GRAPHS * 8 * 256 * sizeof(float);
  int* bsum = (int*)p;        p += 128 * sizeof(int);
  int* boff = (int*)p;        p += 128 * sizeof(int);
  uint2* ebuf = (uint2*)p;    p += (size_t)N_BUCKETS * EBUF_STRIDE * sizeof(uint2);  // 25.6 MB

  // transient CSR-build arrays overlaid into aggr (first written in layer-0 agg)
  int* counts = (int*)aggr;
  int* fill = counts + N_NODES;
  int* bfill = fill + N_NODES;

  // ---- build CSR (once; edge_index is layer-invariant) ----
  hipMemsetAsync(counts, 0, (2 * (size_t)N_NODES + 512) * sizeof(int), stream);
  bucket_count_scatter<<<(N_EDGES + 255) / 256, 256, 0, stream>>>(src, dst, counts,
                                                                  bfill, ebuf);
  inv_kernel<<<(N_NODES + 255) / 256, 256, 0, stream>>>(counts, inv_cnt);
  scan_partial<<<N_SCAN_BLOCKS, 256, 0, stream>>>(counts, bsum);
  scan_bsums<<<1, 128, 0, stream>>>(bsum, boff);
  scan_final<<<N_SCAN_BLOCKS, 256, 0, stream>>>(counts, boff, row_ptr);
  fill_from_ebuf<<<N_BUCKETS * (EBUF_STRIDE / 256), 256, 0, stream>>>(ebuf, bfill,
                                                                     row_ptr, fill, col);

  // ---- one-time converts ----
  convert_x<<<N_NODES / 4, 256, 0, stream>>>((const float4*)x, (ushort4*)h,
                                             (unsigned*)h8);
  convert_w<<<(NLAYERS * 512 * HID) / 256, 256, 0, stream>>>(Wl, Wr, Wt);

  for (int l = 0; l < NLAYERS; l++) {
    aggregate_fp8<<<N_NODES / 4, 256, 0, stream>>>(h8, row_ptr, col, inv_cnt, aggr);
    gemm_fused<<<N_MBLK, 256, 0, stream>>>(h, aggr, Wt + (size_t)l * 512 * HID,
                                           h, psum);
    bn_mid<<<BN_MID, 256, 0, stream>>>(psum, tmp);
    bn_fin<<<1, 256, 0, stream>>>(tmp, gamma + (size_t)l * HID,
                                  beta + (size_t)l * HID, ss);
    if (l < NLAYERS - 1) {
      bn_apply_fused<<<2048, 256, 0, stream>>>((const uint4*)h, ss, (uint4*)h,
                                               (uint2*)h8);
    }
  }

  // layer-3 BN+ReLU fused into two-stage pooling (reads h(=hpre) + ss)
  pool_partial<<<dim3(N_GRAPHS, 8), 256, 0, stream>>>(h, ss, batch, partial);
  pool_mlp_final<<<N_GRAPHS, 256, 0, stream>>>(partial, batch, W1, b1, W2, b2, out);
}

// Round 3
// 942.958 us; speedup vs baseline: 1.5742x; 1.5742x over previous
//
#include <hip/hip_runtime.h>

#define N_NODES 100000
#define M_PAD   100096   // 782 * 128
#define N_MBLK  782
#define N_EDGES 1600000
#define N_GRAPHS 64
#define HID 256
#define PROJ 128
#define NLAYERS 4

#define EBUF_STRIDE 8192
#define N_BUCKETS ((N_NODES + 255) / 256)  // 391
#define CSR_BLK 1024
#define EPT 10
#define CSR_NBLK ((N_EDGES + CSR_BLK * EPT - 1) / (CSR_BLK * EPT))  // 157
#define BFILL_PAD 16  // one counter per 64B line (atomic line-serialization fix)

typedef unsigned short u16;
typedef __attribute__((ext_vector_type(8))) short bf16x8;
typedef __attribute__((ext_vector_type(4))) float f32x4;
typedef __attribute__((ext_vector_type(2))) float vf2;

__device__ __forceinline__ float b2f(u16 u) {
  return __uint_as_float(((unsigned)u) << 16);
}
__device__ __forceinline__ float b2f_lo(unsigned u) {
  return __uint_as_float(u << 16);
}
__device__ __forceinline__ float b2f_hi(unsigned u) {
  return __uint_as_float(u & 0xFFFF0000u);
}
__device__ __forceinline__ u16 f2b(float f) {
  unsigned u = __float_as_uint(f);
  u = (u + 0x7FFF + ((u >> 16) & 1)) >> 16;  // round-to-nearest-even
  return (u16)u;
}
__device__ __forceinline__ void gload16(const void* g, void* l) {
  __builtin_amdgcn_global_load_lds((const __attribute__((address_space(1))) void*)g,
                                   (__attribute__((address_space(3))) void*)l, 16, 0, 0);
}
// ---- fp8 e4m3 (HW cvt; encode/decode self-consistent) ----
__device__ __forceinline__ unsigned pack_fp8x4(float a, float b, float c, float d) {
  int v = __builtin_amdgcn_cvt_pk_fp8_f32(a, b, 0, false);
  v = __builtin_amdgcn_cvt_pk_fp8_f32(c, d, v, true);
  return (unsigned)v;
}
__device__ __forceinline__ void accf8(float* a, unsigned w) {
  vf2 lo = __builtin_amdgcn_cvt_pk_f32_fp8((int)w, false);
  vf2 hi = __builtin_amdgcn_cvt_pk_f32_fp8((int)w, true);
  a[0] += lo.x; a[1] += lo.y; a[2] += hi.x; a[3] += hi.y;
}

// ---------------------------------------------------------------- CSR -------
// Pass A: block-local LDS histogram -> one padded global atomic per
// (block,bucket) -> register-stashed edges scattered as contiguous per-bucket
// runs. Kills the 617us atomic-serialization of the naive per-edge version
// (1.6M atomics on 25 lines ~ 10ns/line-op) and its line ping-pong write amp.
__global__ __launch_bounds__(1024) void bucket_count_scatter(
    const int* __restrict__ src, const int* __restrict__ dst,
    int* __restrict__ cnt, int* __restrict__ bfill, uint2* __restrict__ ebuf) {
  __shared__ int lhist[N_BUCKETS];
  __shared__ int lbase[N_BUCKETS];
  int t = threadIdx.x;
  int e0 = blockIdx.x * (CSR_BLK * EPT) + t;
  for (int i = t; i < N_BUCKETS; i += CSR_BLK) lhist[i] = 0;
  __syncthreads();
  int sv[EPT], dv[EPT];
#pragma unroll
  for (int j = 0; j < EPT; j++) {
    int e = e0 + j * CSR_BLK;
    if (e < N_EDGES) {
      sv[j] = src[e];
      dv[j] = dst[e];
      atomicAdd(&cnt[dv[j]], 1);
      atomicAdd(&lhist[dv[j] >> 8], 1);
    } else {
      dv[j] = -1;
      sv[j] = 0;
    }
  }
  __syncthreads();
  for (int i = t; i < N_BUCKETS; i += CSR_BLK) {
    lbase[i] = atomicAdd(&bfill[i * BFILL_PAD], lhist[i]);
    lhist[i] = 0;  // reuse as block-local fill cursor
  }
  __syncthreads();
#pragma unroll
  for (int j = 0; j < EPT; j++) {
    if (dv[j] >= 0) {
      int b = dv[j] >> 8;
      int p = lbase[b] + atomicAdd(&lhist[b], 1);
      if (p < EBUF_STRIDE) {  // 64-sigma margin; drop-safe guard
        uint2 q;
        q.x = (unsigned)sv[j];
        q.y = (unsigned)dv[j];
        ebuf[(size_t)b * EBUF_STRIDE + p] = q;
      }
    }
  }
}

__global__ void inv_kernel(const int* __restrict__ cnt, float* __restrict__ inv) {
  int n = blockIdx.x * blockDim.x + threadIdx.x;
  if (n < N_NODES) inv[n] = 1.0f / fmaxf((float)cnt[n], 1.0f);
}

#define SCAN_BLK 1024
#define N_SCAN_BLOCKS ((N_NODES + SCAN_BLK - 1) / SCAN_BLK)  // 98

__global__ __launch_bounds__(256) void scan_partial(const int* __restrict__ cnt,
                                                    int* __restrict__ bsum) {
  __shared__ int red[256];
  int t = threadIdx.x;
  int base = blockIdx.x * SCAN_BLK + t * 4;
  int s = 0;
#pragma unroll
  for (int j = 0; j < 4; j++) {
    int i = base + j;
    if (i < N_NODES) s += cnt[i];
  }
  red[t] = s;
  __syncthreads();
  for (int off = 128; off > 0; off >>= 1) {
    if (t < off) red[t] += red[t + off];
    __syncthreads();
  }
  if (t == 0) bsum[blockIdx.x] = red[0];
}

__global__ __launch_bounds__(128) void scan_bsums(const int* __restrict__ bsum,
                                                  int* __restrict__ boff) {
  __shared__ int tile[128];
  int t = threadIdx.x;
  int v = (t < N_SCAN_BLOCKS) ? bsum[t] : 0;
  tile[t] = v;
  __syncthreads();
#pragma unroll
  for (int off = 1; off < 128; off <<= 1) {
    int add = (t >= off) ? tile[t - off] : 0;
    __syncthreads();
    tile[t] += add;
    __syncthreads();
  }
  if (t < N_SCAN_BLOCKS) boff[t] = tile[t] - v;  // exclusive
}

__global__ __launch_bounds__(256) void scan_final(const int* __restrict__ cnt,
                                                  const int* __restrict__ boff,
                                                  int* __restrict__ row_ptr) {
  __shared__ int tsum[256];
  int t = threadIdx.x;
  int base = blockIdx.x * SCAN_BLK + t * 4;
  int v[4];
  int s = 0;
#pragma unroll
  for (int j = 0; j < 4; j++) {
    int i = base + j;
    v[j] = (i < N_NODES) ? cnt[i] : 0;
    s += v[j];
  }
  tsum[t] = s;
  __syncthreads();
#pragma unroll
  for (int off = 1; off < 256; off <<= 1) {
    int add = (t >= off) ? tsum[t - off] : 0;
    __syncthreads();
    tsum[t] += add;
    __syncthreads();
  }
  int excl = tsum[t] - s + boff[blockIdx.x];
#pragma unroll
  for (int j = 0; j < 4; j++) {
    int i = base + j;
    if (i < N_NODES) {
      row_ptr[i] = excl;
      excl += v[j];
    }
  }
  if (blockIdx.x == 0 && t == 0) row_ptr[N_NODES] = N_EDGES;
}

// Pass B: sweep bucket slots; a block's edges share one bucket (256-node dst
// range) so col writes land in a ~16 KB window that stays L2-resident.
__global__ void fill_from_ebuf(const uint2* __restrict__ ebuf,
                               const int* __restrict__ bfill,
                               const int* __restrict__ row_ptr,
                               int* __restrict__ fill,
                               int* __restrict__ col) {
  int idx = blockIdx.x * blockDim.x + threadIdx.x;
  int b = idx >> 13;                 // / EBUF_STRIDE
  int sl = idx & (EBUF_STRIDE - 1);
  if (b < N_BUCKETS && sl < bfill[b * BFILL_PAD]) {
    uint2 q = ebuf[(size_t)b * EBUF_STRIDE + sl];
    int d = (int)q.y;
    int pos = row_ptr[d] + atomicAdd(&fill[d], 1);
    col[pos] = (int)q.x;
  }
}

// ------------------------------------------------------------ converts ------
__global__ __launch_bounds__(256) void convert_x(const float4* __restrict__ x,
                                                 ushort4* __restrict__ hb,
                                                 unsigned* __restrict__ h8) {
  int i = blockIdx.x * blockDim.x + threadIdx.x;  // exactly N_NODES*64 threads
  float4 v = x[i];
  ushort4 o;
  o.x = f2b(v.x); o.y = f2b(v.y); o.z = f2b(v.z); o.w = f2b(v.w);
  hb[i] = o;
  h8[i] = pack_fp8x4(v.x, v.y, v.z, v.w);
}

// Wt[l][n][k] bf16, k<256 -> Wl[l][k][n], k>=256 -> Wr[l][k-256][n]
__global__ __launch_bounds__(256) void convert_w(const float* __restrict__ Wl,
                                                 const float* __restrict__ Wr,
                                                 u16* __restrict__ Wt) {
  int idx = blockIdx.x * blockDim.x + threadIdx.x;  // 4*256*512 threads
  int l = idx >> 17;
  int r = idx & ((1 << 17) - 1);
  int n = r >> 9;
  int k = r & 511;
  float v = (k < 256) ? Wl[(size_t)l * 65536 + k * 256 + n]
                      : Wr[(size_t)l * 65536 + (k - 256) * 256 + n];
  Wt[idx] = f2b(v);
}

// ----------------------------------------------------------- aggregation ----
// one wave per node; two 32-lane halves process alternating edges with 8B fp8
// loads (full 256B row per half); up to 8 gathers in flight per half.
__global__ __launch_bounds__(256) void aggregate_fp8(
    const unsigned char* __restrict__ h8, const int* __restrict__ row_ptr,
    const int* __restrict__ col, const float* __restrict__ inv_cnt,
    u16* __restrict__ aggr) {
  int node = blockIdx.x * 4 + (threadIdx.x >> 6);
  int lane = threadIdx.x & 63;
  int half = lane >> 5, l32 = lane & 31;
  int r0 = row_ptr[node], r1 = row_ptr[node + 1];
  float a[8] = {0.f, 0.f, 0.f, 0.f, 0.f, 0.f, 0.f, 0.f};
  int e = r0 + half;
  for (; e + 14 < r1; e += 16) {
    int s[8];
#pragma unroll
    for (int j = 0; j < 8; j++) s[j] = col[e + 2 * j];
    uint2 v[8];
#pragma unroll
    for (int j = 0; j < 8; j++)
      v[j] = *((const uint2*)(h8 + (size_t)s[j] * HID) + l32);
#pragma unroll
    for (int j = 0; j < 8; j++) { accf8(a, v[j].x); accf8(a + 4, v[j].y); }
  }
  for (; e + 6 < r1; e += 8) {
    int s0 = col[e], s1 = col[e + 2], s2 = col[e + 4], s3 = col[e + 6];
    uint2 v0 = *((const uint2*)(h8 + (size_t)s0 * HID) + l32);
    uint2 v1 = *((const uint2*)(h8 + (size_t)s1 * HID) + l32);
    uint2 v2 = *((const uint2*)(h8 + (size_t)s2 * HID) + l32);
    uint2 v3 = *((const uint2*)(h8 + (size_t)s3 * HID) + l32);
    accf8(a, v0.x); accf8(a + 4, v0.y);
    accf8(a, v1.x); accf8(a + 4, v1.y);
    accf8(a, v2.x); accf8(a + 4, v2.y);
    accf8(a, v3.x); accf8(a + 4, v3.y);
  }
  for (; e < r1; e += 2) {
    int s0 = col[e];
    uint2 v0 = *((const uint2*)(h8 + (size_t)s0 * HID) + l32);
    accf8(a, v0.x); accf8(a + 4, v0.y);
  }
#pragma unroll
  for (int j = 0; j < 8; j++) a[j] += __shfl_xor(a[j], 32, 64);
  if (half == 0) {
    float inv = inv_cnt[node];
    uint4 o;
    o.x = (unsigned)f2b(a[0] * inv) | ((unsigned)f2b(a[1] * inv) << 16);
    o.y = (unsigned)f2b(a[2] * inv) | ((unsigned)f2b(a[3] * inv) << 16);
    o.z = (unsigned)f2b(a[4] * inv) | ((unsigned)f2b(a[5] * inv) << 16);
    o.w = (unsigned)f2b(a[6] * inv) | ((unsigned)f2b(a[7] * inv) << 16);
    *((uint4*)(aggr + (size_t)node * HID) + l32) = o;
  }
}

// ------------------------------------- MFMA GEMM + fused BN partials --------
// hpre[m][n] = sum_k cat(aggr,h)[m][k] * B[k][n];  B^T given as Wt[n][k].
// 128x256 tile, BK=32, 4 waves each 64x128.  hpre may alias hb (in-place):
// each block reads A rows [m0,m0+128) and writes C to exactly those rows,
// with all A reads completing (vmcnt-drained syncthreads) before the C store.
__global__ __launch_bounds__(256, 2) void gemm_fused(
    const u16* hb, const u16* __restrict__ aggr,
    const u16* __restrict__ Bt, u16* hpre,
    float* __restrict__ psum) {
  __shared__ u16 smem[128 * 32 + 256 * 32];  // 24 KB: staging; reused as epilogue buf
  __shared__ float bns[4][8][16][2];         // 4 KB
  u16* As = smem;
  u16* Bs = smem + 128 * 32;
  u16* ep = smem;  // 32 rows x 256 cols bf16 = 16 KB (used after final K-loop sync)

  int tid = threadIdx.x;
  int wid = tid >> 6, lane = tid & 63;
  int m0 = blockIdx.x * 128;
  int q = lane >> 4, c = lane & 15;
  int wm = (wid >> 1) * 64, wn = (wid & 1) * 128;

  f32x4 zero = {0.f, 0.f, 0.f, 0.f};
  f32x4 acc[4][8];
#pragma unroll
  for (int mi = 0; mi < 4; mi++)
#pragma unroll
    for (int ni = 0; ni < 8; ni++) acc[mi][ni] = zero;

  // A staging geometry (2 issues/thread)
  int srowA0 = wid * 32 + (lane >> 2);
  int cgA0 = (lane & 3) ^ ((srowA0 >> 1) & 3);
  int srowA1 = srowA0 + 16;
  int cgA1 = (lane & 3) ^ ((srowA1 >> 1) & 3);
  // B staging geometry (4 issues/thread)
  int srowB[4], cgB[4];
#pragma unroll
  for (int j = 0; j < 4; j++) {
    srowB[j] = j * 64 + wid * 16 + (lane >> 2);
    cgB[j] = (lane & 3) ^ ((srowB[j] >> 1) & 3);
  }

  // frag-read LDS offsets (elements), loop-invariant
  int aoff[4], boff[8];
#pragma unroll
  for (int mi = 0; mi < 4; mi++) {
    int row = wm + mi * 16 + c;
    aoff[mi] = row * 32 + ((q ^ ((row >> 1) & 3)) << 3);
  }
#pragma unroll
  for (int ni = 0; ni < 8; ni++) {
    int row = wn + ni * 16 + c;
    boff[ni] = row * 32 + ((q ^ ((row >> 1) & 3)) << 3);
  }

  for (int k0 = 0; k0 < 512; k0 += 32) {
    const u16* Asrc = (k0 < 256) ? aggr : hb;
    int ksrc = k0 & 255;
    gload16(Asrc + ((size_t)(m0 + srowA0) * HID + ksrc + cgA0 * 8), &As[(wid * 32) * 32]);
    gload16(Asrc + ((size_t)(m0 + srowA1) * HID + ksrc + cgA1 * 8), &As[(wid * 32 + 16) * 32]);
#pragma unroll
    for (int j = 0; j < 4; j++)
      gload16(Bt + ((size_t)srowB[j] * 512 + k0 + cgB[j] * 8), &Bs[(j * 64 + wid * 16) * 32]);
    __syncthreads();
    bf16x8 af[4], bfr[8];
#pragma unroll
    for (int mi = 0; mi < 4; mi++) af[mi] = *(const bf16x8*)&As[aoff[mi]];
#pragma unroll
    for (int ni = 0; ni < 8; ni++) bfr[ni] = *(const bf16x8*)&Bs[boff[ni]];
#pragma unroll
    for (int mi = 0; mi < 4; mi++)
#pragma unroll
      for (int ni = 0; ni < 8; ni++)
        acc[mi][ni] = __builtin_amdgcn_mfma_f32_16x16x32_bf16(af[mi], bfr[ni],
                                                              acc[mi][ni], 0, 0, 0);
    __syncthreads();
  }

  // ---- coalesced C-store: 4 slabs of 32 rows via LDS transpose ----
  int rh = wid >> 1;  // row half (0: rows 0-63, 1: rows 64-127)
#pragma unroll
  for (int mi = 0; mi < 4; mi++) {
#pragma unroll
    for (int r = 0; r < 4; r++) {
      int r16 = q * 4 + r;
#pragma unroll
      for (int ni = 0; ni < 8; ni++)
        ep[(rh * 16 + r16) * 256 + wn + ni * 16 + c] = f2b(acc[mi][ni][r]);
    }
    __syncthreads();
    int u = tid;
#pragma unroll
    for (int j = 0; j < 4; j++, u += 256) {
      int lr = u >> 5;     // 0..31 local row
      int cu = u & 31;     // uint4 column
      int gm = m0 + (lr >> 4) * 64 + mi * 16 + (lr & 15);
      if (gm < N_NODES)
        ((uint4*)(hpre + (size_t)gm * HID))[cu] = ((const uint4*)ep)[u];
    }
    __syncthreads();
  }

  // ---- BN column partials from fp32 acc (mask pad rows) ----
#pragma unroll
  for (int ni = 0; ni < 8; ni++) {
    float s = 0.f, s2 = 0.f;
#pragma unroll
    for (int mi = 0; mi < 4; mi++) {
#pragma unroll
      for (int r = 0; r < 4; r++) {
        int gm = m0 + wm + mi * 16 + q * 4 + r;
        float v = (gm < N_NODES) ? acc[mi][ni][r] : 0.f;
        s += v;
        s2 += v * v;
      }
    }
    s += __shfl_xor(s, 16, 64);
    s += __shfl_xor(s, 32, 64);
    s2 += __shfl_xor(s2, 16, 64);
    s2 += __shfl_xor(s2, 32, 64);
    if (q == 0) {
      bns[wid][ni][c][0] = s;
      bns[wid][ni][c][1] = s2;
    }
  }
  __syncthreads();
  {
    int wnh = tid >> 7, ni = (tid >> 4) & 7, cc = tid & 15;
    float s = bns[wnh][ni][cc][0] + bns[wnh + 2][ni][cc][0];
    float s2 = bns[wnh][ni][cc][1] + bns[wnh + 2][ni][cc][1];
    int coln = wnh * 128 + ni * 16 + cc;
    psum[(size_t)blockIdx.x * 512 + coln] = s;
    psum[(size_t)blockIdx.x * 512 + 256 + coln] = s2;
  }
}

// --------------------------------- BN reduce (tree, atomic-free) ------------
#define BN_MID 16
__global__ __launch_bounds__(256) void bn_mid(const float* __restrict__ psum,
                                              float* __restrict__ tmp) {
  int b = blockIdx.x;
  int f = threadIdx.x;
  int mb0 = b * 49;
  int mb1 = min(mb0 + 49, N_MBLK);
  float s = 0.f, s2 = 0.f;
  for (int mb = mb0; mb < mb1; mb++) {
    s += psum[(size_t)mb * 512 + f];
    s2 += psum[(size_t)mb * 512 + 256 + f];
  }
  tmp[(size_t)b * 512 + f] = s;
  tmp[(size_t)b * 512 + 256 + f] = s2;
}

__global__ void bn_fin(const float* __restrict__ tmp,
                       const float* __restrict__ gamma,
                       const float* __restrict__ beta,
                       float* __restrict__ ss) {
  int f = threadIdx.x;
  float sum = 0.f, sq = 0.f;
#pragma unroll
  for (int b = 0; b < BN_MID; b++) {
    sum += tmp[(size_t)b * 512 + f];
    sq += tmp[(size_t)b * 512 + 256 + f];
  }
  const float invN = 1.0f / (float)N_NODES;
  float mu = sum * invN;
  float ex2 = sq * invN;
  float var = fmaxf(ex2 - mu * mu, 0.f);
  float sc = gamma[f] * rsqrtf(var + 1e-5f);
  ss[f] = sc;
  ss[HID + f] = beta[f] - mu * sc;
}

// BN+ReLU apply, in-place on the bf16 h buffer, plus fp8 shadow copy for the
// next layer's aggregation gather.
__global__ __launch_bounds__(256) void bn_apply_fused(const uint4* hpre,
                                                      const float* __restrict__ ss,
                                                      uint4* hout,
                                                      uint2* __restrict__ h8out) {
  int idx0 = blockIdx.x * blockDim.x + threadIdx.x;
  int cb = (idx0 & 31) * 8;  // column base (row = 32 uint4)
  float sc[8], sh[8];
#pragma unroll
  for (int j = 0; j < 8; j++) { sc[j] = ss[cb + j]; sh[j] = ss[HID + cb + j]; }
  const int total = N_NODES * 32;
  const int step = gridDim.x * blockDim.x;  // 524288, multiple of 32
  for (int i = idx0; i < total; i += step) {
    uint4 v = hpre[i];
    unsigned vv[4] = {v.x, v.y, v.z, v.w};
    unsigned o[4];
    float f[8];
#pragma unroll
    for (int j = 0; j < 4; j++) {
      float lo = fmaxf(fmaf(b2f_lo(vv[j]), sc[2 * j], sh[2 * j]), 0.f);
      float hi = fmaxf(fmaf(b2f_hi(vv[j]), sc[2 * j + 1], sh[2 * j + 1]), 0.f);
      f[2 * j] = lo;
      f[2 * j + 1] = hi;
      o[j] = (unsigned)f2b(lo) | ((unsigned)f2b(hi) << 16);
    }
    uint4 ov = {o[0], o[1], o[2], o[3]};
    hout[i] = ov;
    uint2 q;
    q.x = pack_fp8x4(f[0], f[1], f[2], f[3]);
    q.y = pack_fp8x4(f[4], f[5], f[6], f[7]);
    h8out[i] = q;
  }
}

// ---------------- pool stage 1: per-(graph, chunk) BN+ReLU partial sums -----
// grid (64, 8); each block covers 1/8 of its graph's rows; atomic-free.
__global__ __launch_bounds__(256) void pool_partial(
    const u16* __restrict__ hpre, const float* __restrict__ ss,
    const int* __restrict__ batch, float* __restrict__ partial) {
  __shared__ float red[256][9];
  int g = blockIdx.x;
  int i = blockIdx.y;
  int t = threadIdx.x;
  // row range of graph g in sorted batch: [lo, hi)
  int a = 0, b = N_NODES;
  while (a < b) { int m = (a + b) >> 1; if (batch[m] < g) a = m + 1; else b = m; }
  int lo = a;
  b = N_NODES;
  while (a < b) { int m = (a + b) >> 1; if (batch[m] < g + 1) a = m + 1; else b = m; }
  int hi = a;
  int len = hi - lo;
  int clen = (len + 7) >> 3;
  int c0 = lo + i * clen;
  int c1 = min(c0 + clen, hi);

  int rs = t >> 5, cu = t & 31;
  int cb = cu * 8;
  float scv[8], shv[8];
#pragma unroll
  for (int j = 0; j < 8; j++) { scv[j] = ss[cb + j]; shv[j] = ss[HID + cb + j]; }
  float acc[8] = {0.f, 0.f, 0.f, 0.f, 0.f, 0.f, 0.f, 0.f};
  for (int r = c0 + rs; r < c1; r += 8) {
    uint4 v = *((const uint4*)(hpre + (size_t)r * HID) + cu);
    unsigned vv[4] = {v.x, v.y, v.z, v.w};
#pragma unroll
    for (int j = 0; j < 4; j++) {
      acc[2 * j]     += fmaxf(fmaf(b2f_lo(vv[j]), scv[2 * j], shv[2 * j]), 0.f);
      acc[2 * j + 1] += fmaxf(fmaf(b2f_hi(vv[j]), scv[2 * j + 1], shv[2 * j + 1]), 0.f);
    }
  }
#pragma unroll
  for (int j = 0; j < 8; j++) red[t][j] = acc[j];
  __syncthreads();
  // thread t reduces column t across the 8 row-strips
  int cc = t >> 3, j = t & 7;
  float sum = 0.f;
#pragma unroll
  for (int k = 0; k < 8; k++) sum += red[k * 32 + cc][j];
  partial[((size_t)g * 8 + i) * 256 + t] = sum;
}

// ---------------- pool stage 2 + MLP (64 blocks, reads 8 partials/graph) ----
__global__ __launch_bounds__(256) void pool_mlp_final(
    const float* __restrict__ partial, const int* __restrict__ batch,
    const float* __restrict__ W1, const float* __restrict__ b1,
    const float* __restrict__ W2, const float* __restrict__ b2,
    float* __restrict__ out) {
  __shared__ float gs[HID];
  __shared__ float ts[HID];
  __shared__ float rn[PROJ];
  int g = blockIdx.x;
  int t = threadIdx.x;
  // graph length via binary search
  int a = 0, b = N_NODES;
  while (a < b) { int m = (a + b) >> 1; if (batch[m] < g) a = m + 1; else b = m; }
  int lo = a;
  b = N_NODES;
  while (a < b) { int m = (a + b) >> 1; if (batch[m] < g + 1) a = m + 1; else b = m; }
  int len = a - lo;

  float sum = 0.f;
#pragma unroll
  for (int i = 0; i < 8; i++) sum += partial[((size_t)g * 8 + i) * 256 + t];
  float inv = 1.0f / fmaxf((float)len, 1.0f);
  gs[t] = sum * inv;
  __syncthreads();

  float s = b1[t];
  for (int k = 0; k < HID; k++) s = fmaf(gs[k], W1[(size_t)k * HID + t], s);
  ts[t] = fmaxf(s, 0.f);
  __syncthreads();
  float z = 0.f;
  if (t < PROJ) {
    z = b2[t];
    for (int k = 0; k < HID; k++) z = fmaf(ts[k], W2[(size_t)k * PROJ + t], z);
    rn[t] = z * z;
  }
  __syncthreads();
  for (int off = PROJ / 2; off > 0; off >>= 1) {
    if (t < off) rn[t] += rn[t + off];
    __syncthreads();
  }
  float norm = fmaxf(sqrtf(rn[0]), 1e-12f);
  if (t < PROJ) out[(size_t)g * PROJ + t] = z / norm;
}

// --------------------------------------------------------------- launch -----
extern "C" void kernel_launch(void* const* d_in, const int* in_sizes, int n_in,
                              void* d_out, int out_size, void* d_ws, size_t ws_size,
                              hipStream_t stream) {
  const float* x = (const float*)d_in[0];
  const int* ei = (const int*)d_in[1];
  const int* src = ei;
  const int* dst = ei + N_EDGES;
  const int* batch = (const int*)d_in[2];
  const float* Wl = (const float*)d_in[3];
  // d_in[4] = bl: per-column bias is exactly cancelled by BatchNorm -> unused
  const float* Wr = (const float*)d_in[5];
  const float* gamma = (const float*)d_in[6];
  const float* beta = (const float*)d_in[7];
  const float* W1 = (const float*)d_in[8];
  const float* b1 = (const float*)d_in[9];
  const float* W2 = (const float*)d_in[10];
  const float* b2 = (const float*)d_in[11];
  float* out = (float*)d_out;

  char* p = (char*)d_ws;
  const size_t HB = (size_t)M_PAD * HID * sizeof(u16);  // 51.25 MB
  u16* h = (u16*)p;      p += HB;                        // bf16 h / hpre (in-place)
  u16* aggr = (u16*)p;   p += HB;
  unsigned char* h8 = (unsigned char*)p; p += (size_t)M_PAD * HID;  // 25.6 MB fp8
  u16* Wt = (u16*)p;     p += (size_t)NLAYERS * 512 * HID * sizeof(u16);  // 1 MB
  int* col = (int*)p;    p += (size_t)N_EDGES * sizeof(int);              // 6.4 MB
  int* row_ptr = (int*)p; p += 400016;
  float* inv_cnt = (float*)p; p += (size_t)N_NODES * sizeof(float);
  float* psum = (float*)p;    p += (size_t)N_MBLK * 512 * sizeof(float);  // 1.6 MB
  float* tmp = (float*)p;     p += (size_t)BN_MID * 512 * sizeof(float);
  float* ss = (float*)p;      p += 512 * sizeof(float);
  float* partial = (float*)p; p += (size_t)N_GRAPHS * 8 * 256 * sizeof(float);
  int* bsum = (int*)p;        p += 128 * sizeof(int);
  int* boff = (int*)p;        p += 128 * sizeof(int);
  uint2* ebuf = (uint2*)p;    p += (size_t)N_BUCKETS * EBUF_STRIDE * sizeof(uint2);  // 25.6 MB

  // transient CSR-build arrays overlaid into aggr (first written in layer-0 agg)
  int* counts = (int*)aggr;
  int* fill = counts + N_NODES;
  int* bfill = fill + N_NODES;  // padded: N_BUCKETS * BFILL_PAD ints

  // ---- build CSR (once; edge_index is layer-invariant) ----
  hipMemsetAsync(counts, 0,
                 (2 * (size_t)N_NODES + N_BUCKETS * BFILL_PAD) * sizeof(int), stream);
  bucket_count_scatter<<<CSR_NBLK, CSR_BLK, 0, stream>>>(src, dst, counts,
                                                         bfill, ebuf);
  inv_kernel<<<(N_NODES + 255) / 256, 256, 0, stream>>>(counts, inv_cnt);
  scan_partial<<<N_SCAN_BLOCKS, 256, 0, stream>>>(counts, bsum);
  scan_bsums<<<1, 128, 0, stream>>>(bsum, boff);
  scan_final<<<N_SCAN_BLOCKS, 256, 0, stream>>>(counts, boff, row_ptr);
  fill_from_ebuf<<<N_BUCKETS * (EBUF_STRIDE / 256), 256, 0, stream>>>(ebuf, bfill,
                                                                     row_ptr, fill, col);

  // ---- one-time converts ----
  convert_x<<<N_NODES / 4, 256, 0, stream>>>((const float4*)x, (ushort4*)h,
                                             (unsigned*)h8);
  convert_w<<<(NLAYERS * 512 * HID) / 256, 256, 0, stream>>>(Wl, Wr, Wt);

  for (int l = 0; l < NLAYERS; l++) {
    aggregate_fp8<<<N_NODES / 4, 256, 0, stream>>>(h8, row_ptr, col, inv_cnt, aggr);
    gemm_fused<<<N_MBLK, 256, 0, stream>>>(h, aggr, Wt + (size_t)l * 512 * HID,
                                           h, psum);
    bn_mid<<<BN_MID, 256, 0, stream>>>(psum, tmp);
    bn_fin<<<1, 256, 0, stream>>>(tmp, gamma + (size_t)l * HID,
                                  beta + (size_t)l * HID, ss);
    if (l < NLAYERS - 1) {
      bn_apply_fused<<<2048, 256, 0, stream>>>((const uint4*)h, ss, (uint4*)h,
                                               (uint2*)h8);
    }
  }

  // layer-3 BN+ReLU fused into two-stage pooling (reads h(=hpre) + ss)
  pool_partial<<<dim3(N_GRAPHS, 8), 256, 0, stream>>>(h, ss, batch, partial);
  pool_mlp_final<<<N_GRAPHS, 256, 0, stream>>>(partial, batch, W1, b1, W2, b2, out);
}

// Round 4
// 849.265 us; speedup vs baseline: 1.7478x; 1.1103x over previous
//
#include <hip/hip_runtime.h>

#define N_NODES 100000
#define M_PAD   100096   // 782 * 128
#define N_MBLK  782
#define N_EDGES 1600000
#define N_GRAPHS 64
#define HID 256
#define PROJ 128
#define NLAYERS 4

#define EBUF_STRIDE 8192
#define N_BUCKETS ((N_NODES + 255) / 256)  // 391
#define CSR_BLK 1024
#define EPT 10
#define CSR_NBLK ((N_EDGES + CSR_BLK * EPT - 1) / (CSR_BLK * EPT))  // 157
#define SENT 0xFFFFFFFFu

typedef unsigned short u16;
typedef unsigned long long u64;
typedef __attribute__((ext_vector_type(8))) short bf16x8;
typedef __attribute__((ext_vector_type(4))) float f32x4;
typedef __attribute__((ext_vector_type(2))) float vf2;

__device__ __forceinline__ float b2f(u16 u) {
  return __uint_as_float(((unsigned)u) << 16);
}
__device__ __forceinline__ float b2f_lo(unsigned u) {
  return __uint_as_float(u << 16);
}
__device__ __forceinline__ float b2f_hi(unsigned u) {
  return __uint_as_float(u & 0xFFFF0000u);
}
__device__ __forceinline__ u16 f2b(float f) {
  unsigned u = __float_as_uint(f);
  u = (u + 0x7FFF + ((u >> 16) & 1)) >> 16;  // round-to-nearest-even
  return (u16)u;
}
__device__ __forceinline__ void gload16(const void* g, void* l) {
  __builtin_amdgcn_global_load_lds((const __attribute__((address_space(1))) void*)g,
                                   (__attribute__((address_space(3))) void*)l, 16, 0, 0);
}
// ---- fp8 e4m3 (HW cvt; encode/decode self-consistent) ----
__device__ __forceinline__ unsigned pack_fp8x4(float a, float b, float c, float d) {
  int v = __builtin_amdgcn_cvt_pk_fp8_f32(a, b, 0, false);
  v = __builtin_amdgcn_cvt_pk_fp8_f32(c, d, v, true);
  return (unsigned)v;
}
__device__ __forceinline__ void accf8(float* a, unsigned w) {
  vf2 lo = __builtin_amdgcn_cvt_pk_f32_fp8((int)w, false);
  vf2 hi = __builtin_amdgcn_cvt_pk_f32_fp8((int)w, true);
  a[0] += lo.x; a[1] += lo.y; a[2] += hi.x; a[3] += hi.y;
}

// ---------------------------------------------------------------- CSR -------
// Pass A: bucket scatter only (no per-node count atomics -- those were ~50MB
// of near-memory RMW traffic). Per-(block,bucket) runs are reserved 64B-line
// aligned via ONE packed 64-bit atomic (alloc<<32 | valid); pad slots get
// sentinels written by the owning block, so every ebuf line has exactly one
// writer -> write amp ~1.1x.
__global__ __launch_bounds__(1024) void bucket_scatter(
    const int* __restrict__ src, const int* __restrict__ dst,
    u64* __restrict__ bfill64, uint2* __restrict__ ebuf) {
  __shared__ int lhist[N_BUCKETS];
  __shared__ int lbase[N_BUCKETS];
  int t = threadIdx.x;
  int e0 = blockIdx.x * (CSR_BLK * EPT) + t;
  for (int i = t; i < N_BUCKETS; i += CSR_BLK) lhist[i] = 0;
  __syncthreads();
  int sv[EPT], dv[EPT];
#pragma unroll
  for (int j = 0; j < EPT; j++) {
    int e = e0 + j * CSR_BLK;
    if (e < N_EDGES) {
      sv[j] = src[e];
      dv[j] = dst[e];
      atomicAdd(&lhist[dv[j] >> 8], 1);
    } else {
      dv[j] = -1;
      sv[j] = 0;
    }
  }
  __syncthreads();
  for (int i = t; i < N_BUCKETS; i += CSR_BLK) {
    int c = lhist[i];
    if (c > 0) {
      int rounded = (c + 7) & ~7;  // 8 slots = 64B line alignment
      u64 old = atomicAdd(&bfill64[(size_t)i * 8],
                          ((u64)rounded << 32) | (u64)c);
      int base = (int)(old >> 32);
      lbase[i] = base;
      for (int k = c; k < rounded; k++) {  // self-write pad sentinels
        int p = base + k;
        if (p < EBUF_STRIDE) {
          uint2 q; q.x = 0; q.y = SENT;
          ebuf[(size_t)i * EBUF_STRIDE + p] = q;
        }
      }
      lhist[i] = 0;  // reuse as block-local fill cursor
    }
  }
  __syncthreads();
#pragma unroll
  for (int j = 0; j < EPT; j++) {
    if (dv[j] >= 0) {
      int b = dv[j] >> 8;
      int p = lbase[b] + atomicAdd(&lhist[b], 1);
      if (p < EBUF_STRIDE) {  // ~47-sigma margin; drop-safe guard
        uint2 q;
        q.x = (unsigned)sv[j];
        q.y = (unsigned)dv[j];
        ebuf[(size_t)b * EBUF_STRIDE + p] = q;
      }
    }
  }
}

// Pass A1: scan 391 per-bucket valid counts -> bucket bases + total.
__global__ __launch_bounds__(512) void bucket_prefix(
    const u64* __restrict__ bfill64, int* __restrict__ bucket_base,
    int* __restrict__ row_ptr) {
  __shared__ int tile[512];
  int t = threadIdx.x;
  int v = 0;
  if (t < N_BUCKETS) {
    u64 w = bfill64[(size_t)t * 8];
    v = (int)(w & 0xFFFFFFFFull);
    if ((int)(w >> 32) > EBUF_STRIDE) v = min(v, EBUF_STRIDE);  // degenerate clamp
  }
  tile[t] = v;
  __syncthreads();
  for (int off = 1; off < 512; off <<= 1) {
    int add = (t >= off) ? tile[t - off] : 0;
    __syncthreads();
    tile[t] += add;
    __syncthreads();
  }
  if (t < N_BUCKETS) bucket_base[t] = tile[t] - v;  // exclusive
  if (t == N_BUCKETS - 1) row_ptr[N_NODES] = tile[t];
}

// Pass B: one block per bucket. LDS-only atomics: 256-bin histogram ->
// exclusive scan -> row_ptr/inv_cnt written coalesced; edges placed via LDS
// cursors into a ~16KB col window owned by this single CU (one-XCD L2
// write-back, amp ~1).
__global__ __launch_bounds__(1024) void csr_build(
    const uint2* __restrict__ ebuf, const u64* __restrict__ bfill64,
    const int* __restrict__ bucket_base, int* __restrict__ row_ptr,
    float* __restrict__ inv_cnt, int* __restrict__ col) {
  __shared__ int hist[256];
  __shared__ int nscan[256];
  __shared__ int cursor[256];
  int b = blockIdx.x;
  int t = threadIdx.x;
  int nalloc = min((int)(bfill64[(size_t)b * 8] >> 32), EBUF_STRIDE);
  int bbase = bucket_base[b];
  if (t < 256) hist[t] = 0;
  __syncthreads();
  uint2 q[8];
#pragma unroll
  for (int k = 0; k < 8; k++) {
    int i = t + k * CSR_BLK;
    q[k].x = 0; q[k].y = SENT;
    if (i < nalloc) {
      q[k] = ebuf[(size_t)b * EBUF_STRIDE + i];
      if (q[k].y != SENT) atomicAdd(&hist[q[k].y & 255], 1);
    }
  }
  __syncthreads();
  if (t < 256) nscan[t] = hist[t];
  __syncthreads();
  for (int off = 1; off < 256; off <<= 1) {
    int add = 0;
    if (t < 256 && t >= off) add = nscan[t - off];
    __syncthreads();
    if (t < 256) nscan[t] += add;
    __syncthreads();
  }
  int nb = min(256, N_NODES - b * 256);
  if (t < 256) {
    int excl = nscan[t] - hist[t];
    cursor[t] = excl;
    if (t < nb) {
      row_ptr[b * 256 + t] = bbase + excl;
      inv_cnt[b * 256 + t] = 1.0f / fmaxf((float)hist[t], 1.0f);
    }
  }
  __syncthreads();
#pragma unroll
  for (int k = 0; k < 8; k++) {
    if (q[k].y != SENT) {
      int l = (int)(q[k].y & 255);
      int pos = bbase + atomicAdd(&cursor[l], 1);
      col[pos] = (int)q[k].x;
    }
  }
}

// ------------------------------------------------------------ converts ------
__global__ __launch_bounds__(256) void convert_x(const float4* __restrict__ x,
                                                 ushort4* __restrict__ hb,
                                                 unsigned* __restrict__ h8) {
  int i = blockIdx.x * blockDim.x + threadIdx.x;  // exactly N_NODES*64 threads
  float4 v = x[i];
  ushort4 o;
  o.x = f2b(v.x); o.y = f2b(v.y); o.z = f2b(v.z); o.w = f2b(v.w);
  hb[i] = o;
  h8[i] = pack_fp8x4(v.x, v.y, v.z, v.w);
}

// Wt[l][n][k] bf16, k<256 -> Wl[l][k][n], k>=256 -> Wr[l][k-256][n]
__global__ __launch_bounds__(256) void convert_w(const float* __restrict__ Wl,
                                                 const float* __restrict__ Wr,
                                                 u16* __restrict__ Wt) {
  int idx = blockIdx.x * blockDim.x + threadIdx.x;  // 4*256*512 threads
  int l = idx >> 17;
  int r = idx & ((1 << 17) - 1);
  int n = r >> 9;
  int k = r & 511;
  float v = (k < 256) ? Wl[(size_t)l * 65536 + k * 256 + n]
                      : Wr[(size_t)l * 65536 + (k - 256) * 256 + n];
  Wt[idx] = f2b(v);
}

// ----------------------------------------------------------- aggregation ----
// one wave per node; two 32-lane halves process alternating edges with 8B fp8
// loads (full 256B row per half); up to 8 gathers in flight per half.
__global__ __launch_bounds__(256) void aggregate_fp8(
    const unsigned char* __restrict__ h8, const int* __restrict__ row_ptr,
    const int* __restrict__ col, const float* __restrict__ inv_cnt,
    u16* __restrict__ aggr) {
  int node = blockIdx.x * 4 + (threadIdx.x >> 6);
  int lane = threadIdx.x & 63;
  int half = lane >> 5, l32 = lane & 31;
  int r0 = row_ptr[node], r1 = row_ptr[node + 1];
  float a[8] = {0.f, 0.f, 0.f, 0.f, 0.f, 0.f, 0.f, 0.f};
  int e = r0 + half;
  for (; e + 14 < r1; e += 16) {
    int s[8];
#pragma unroll
    for (int j = 0; j < 8; j++) s[j] = col[e + 2 * j];
    uint2 v[8];
#pragma unroll
    for (int j = 0; j < 8; j++)
      v[j] = *((const uint2*)(h8 + (size_t)s[j] * HID) + l32);
#pragma unroll
    for (int j = 0; j < 8; j++) { accf8(a, v[j].x); accf8(a + 4, v[j].y); }
  }
  for (; e + 6 < r1; e += 8) {
    int s0 = col[e], s1 = col[e + 2], s2 = col[e + 4], s3 = col[e + 6];
    uint2 v0 = *((const uint2*)(h8 + (size_t)s0 * HID) + l32);
    uint2 v1 = *((const uint2*)(h8 + (size_t)s1 * HID) + l32);
    uint2 v2 = *((const uint2*)(h8 + (size_t)s2 * HID) + l32);
    uint2 v3 = *((const uint2*)(h8 + (size_t)s3 * HID) + l32);
    accf8(a, v0.x); accf8(a + 4, v0.y);
    accf8(a, v1.x); accf8(a + 4, v1.y);
    accf8(a, v2.x); accf8(a + 4, v2.y);
    accf8(a, v3.x); accf8(a + 4, v3.y);
  }
  for (; e < r1; e += 2) {
    int s0 = col[e];
    uint2 v0 = *((const uint2*)(h8 + (size_t)s0 * HID) + l32);
    accf8(a, v0.x); accf8(a + 4, v0.y);
  }
#pragma unroll
  for (int j = 0; j < 8; j++) a[j] += __shfl_xor(a[j], 32, 64);
  if (half == 0) {
    float inv = inv_cnt[node];
    uint4 o;
    o.x = (unsigned)f2b(a[0] * inv) | ((unsigned)f2b(a[1] * inv) << 16);
    o.y = (unsigned)f2b(a[2] * inv) | ((unsigned)f2b(a[3] * inv) << 16);
    o.z = (unsigned)f2b(a[4] * inv) | ((unsigned)f2b(a[5] * inv) << 16);
    o.w = (unsigned)f2b(a[6] * inv) | ((unsigned)f2b(a[7] * inv) << 16);
    *((uint4*)(aggr + (size_t)node * HID) + l32) = o;
  }
}

// ------------------------------------- MFMA GEMM + fused BN partials --------
// hpre[m][n] = sum_k cat(aggr,h)[m][k] * B[k][n];  B^T given as Wt[n][k].
// 128x256 tile, BK=32, 4 waves each 64x128.  hpre may alias hb (in-place):
// each block reads A rows [m0,m0+128) and writes C to exactly those rows,
// with all A reads completing (vmcnt-drained syncthreads) before the C store.
__global__ __launch_bounds__(256, 2) void gemm_fused(
    const u16* hb, const u16* __restrict__ aggr,
    const u16* __restrict__ Bt, u16* hpre,
    float* __restrict__ psum) {
  __shared__ u16 smem[128 * 32 + 256 * 32];  // 24 KB: staging; reused as epilogue buf
  __shared__ float bns[4][8][16][2];         // 4 KB
  u16* As = smem;
  u16* Bs = smem + 128 * 32;
  u16* ep = smem;  // 32 rows x 256 cols bf16 = 16 KB (used after final K-loop sync)

  int tid = threadIdx.x;
  int wid = tid >> 6, lane = tid & 63;
  int m0 = blockIdx.x * 128;
  int q = lane >> 4, c = lane & 15;
  int wm = (wid >> 1) * 64, wn = (wid & 1) * 128;

  f32x4 zero = {0.f, 0.f, 0.f, 0.f};
  f32x4 acc[4][8];
#pragma unroll
  for (int mi = 0; mi < 4; mi++)
#pragma unroll
    for (int ni = 0; ni < 8; ni++) acc[mi][ni] = zero;

  // A staging geometry (2 issues/thread)
  int srowA0 = wid * 32 + (lane >> 2);
  int cgA0 = (lane & 3) ^ ((srowA0 >> 1) & 3);
  int srowA1 = srowA0 + 16;
  int cgA1 = (lane & 3) ^ ((srowA1 >> 1) & 3);
  // B staging geometry (4 issues/thread)
  int srowB[4], cgB[4];
#pragma unroll
  for (int j = 0; j < 4; j++) {
    srowB[j] = j * 64 + wid * 16 + (lane >> 2);
    cgB[j] = (lane & 3) ^ ((srowB[j] >> 1) & 3);
  }

  // frag-read LDS offsets (elements), loop-invariant
  int aoff[4], boff[8];
#pragma unroll
  for (int mi = 0; mi < 4; mi++) {
    int row = wm + mi * 16 + c;
    aoff[mi] = row * 32 + ((q ^ ((row >> 1) & 3)) << 3);
  }
#pragma unroll
  for (int ni = 0; ni < 8; ni++) {
    int row = wn + ni * 16 + c;
    boff[ni] = row * 32 + ((q ^ ((row >> 1) & 3)) << 3);
  }

  for (int k0 = 0; k0 < 512; k0 += 32) {
    const u16* Asrc = (k0 < 256) ? aggr : hb;
    int ksrc = k0 & 255;
    gload16(Asrc + ((size_t)(m0 + srowA0) * HID + ksrc + cgA0 * 8), &As[(wid * 32) * 32]);
    gload16(Asrc + ((size_t)(m0 + srowA1) * HID + ksrc + cgA1 * 8), &As[(wid * 32 + 16) * 32]);
#pragma unroll
    for (int j = 0; j < 4; j++)
      gload16(Bt + ((size_t)srowB[j] * 512 + k0 + cgB[j] * 8), &Bs[(j * 64 + wid * 16) * 32]);
    __syncthreads();
    bf16x8 af[4], bfr[8];
#pragma unroll
    for (int mi = 0; mi < 4; mi++) af[mi] = *(const bf16x8*)&As[aoff[mi]];
#pragma unroll
    for (int ni = 0; ni < 8; ni++) bfr[ni] = *(const bf16x8*)&Bs[boff[ni]];
#pragma unroll
    for (int mi = 0; mi < 4; mi++)
#pragma unroll
      for (int ni = 0; ni < 8; ni++)
        acc[mi][ni] = __builtin_amdgcn_mfma_f32_16x16x32_bf16(af[mi], bfr[ni],
                                                              acc[mi][ni], 0, 0, 0);
    __syncthreads();
  }

  // ---- coalesced C-store: 4 slabs of 32 rows via LDS transpose ----
  int rh = wid >> 1;  // row half (0: rows 0-63, 1: rows 64-127)
#pragma unroll
  for (int mi = 0; mi < 4; mi++) {
#pragma unroll
    for (int r = 0; r < 4; r++) {
      int r16 = q * 4 + r;
#pragma unroll
      for (int ni = 0; ni < 8; ni++)
        ep[(rh * 16 + r16) * 256 + wn + ni * 16 + c] = f2b(acc[mi][ni][r]);
    }
    __syncthreads();
    int u = tid;
#pragma unroll
    for (int j = 0; j < 4; j++, u += 256) {
      int lr = u >> 5;     // 0..31 local row
      int cu = u & 31;     // uint4 column
      int gm = m0 + (lr >> 4) * 64 + mi * 16 + (lr & 15);
      if (gm < N_NODES)
        ((uint4*)(hpre + (size_t)gm * HID))[cu] = ((const uint4*)ep)[u];
    }
    __syncthreads();
  }

  // ---- BN column partials from fp32 acc (mask pad rows) ----
#pragma unroll
  for (int ni = 0; ni < 8; ni++) {
    float s = 0.f, s2 = 0.f;
#pragma unroll
    for (int mi = 0; mi < 4; mi++) {
#pragma unroll
      for (int r = 0; r < 4; r++) {
        int gm = m0 + wm + mi * 16 + q * 4 + r;
        float v = (gm < N_NODES) ? acc[mi][ni][r] : 0.f;
        s += v;
        s2 += v * v;
      }
    }
    s += __shfl_xor(s, 16, 64);
    s += __shfl_xor(s, 32, 64);
    s2 += __shfl_xor(s2, 16, 64);
    s2 += __shfl_xor(s2, 32, 64);
    if (q == 0) {
      bns[wid][ni][c][0] = s;
      bns[wid][ni][c][1] = s2;
    }
  }
  __syncthreads();
  {
    int wnh = tid >> 7, ni = (tid >> 4) & 7, cc = tid & 15;
    float s = bns[wnh][ni][cc][0] + bns[wnh + 2][ni][cc][0];
    float s2 = bns[wnh][ni][cc][1] + bns[wnh + 2][ni][cc][1];
    int coln = wnh * 128 + ni * 16 + cc;
    psum[(size_t)blockIdx.x * 512 + coln] = s;
    psum[(size_t)blockIdx.x * 512 + 256 + coln] = s2;
  }
}

// --------------------------------- BN reduce (tree, atomic-free) ------------
#define BN_MID 16
__global__ __launch_bounds__(256) void bn_mid(const float* __restrict__ psum,
                                              float* __restrict__ tmp) {
  int b = blockIdx.x;
  int f = threadIdx.x;
  int mb0 = b * 49;
  int mb1 = min(mb0 + 49, N_MBLK);
  float s = 0.f, s2 = 0.f;
  for (int mb = mb0; mb < mb1; mb++) {
    s += psum[(size_t)mb * 512 + f];
    s2 += psum[(size_t)mb * 512 + 256 + f];
  }
  tmp[(size_t)b * 512 + f] = s;
  tmp[(size_t)b * 512 + 256 + f] = s2;
}

__global__ void bn_fin(const float* __restrict__ tmp,
                       const float* __restrict__ gamma,
                       const float* __restrict__ beta,
                       float* __restrict__ ss) {
  int f = threadIdx.x;
  float sum = 0.f, sq = 0.f;
#pragma unroll
  for (int b = 0; b < BN_MID; b++) {
    sum += tmp[(size_t)b * 512 + f];
    sq += tmp[(size_t)b * 512 + 256 + f];
  }
  const float invN = 1.0f / (float)N_NODES;
  float mu = sum * invN;
  float ex2 = sq * invN;
  float var = fmaxf(ex2 - mu * mu, 0.f);
  float sc = gamma[f] * rsqrtf(var + 1e-5f);
  ss[f] = sc;
  ss[HID + f] = beta[f] - mu * sc;
}

// BN+ReLU apply, in-place on the bf16 h buffer, plus fp8 shadow copy for the
// next layer's aggregation gather.
__global__ __launch_bounds__(256) void bn_apply_fused(const uint4* hpre,
                                                      const float* __restrict__ ss,
                                                      uint4* hout,
                                                      uint2* __restrict__ h8out) {
  int idx0 = blockIdx.x * blockDim.x + threadIdx.x;
  int cb = (idx0 & 31) * 8;  // column base (row = 32 uint4)
  float sc[8], sh[8];
#pragma unroll
  for (int j = 0; j < 8; j++) { sc[j] = ss[cb + j]; sh[j] = ss[HID + cb + j]; }
  const int total = N_NODES * 32;
  const int step = gridDim.x * blockDim.x;  // 524288, multiple of 32
  for (int i = idx0; i < total; i += step) {
    uint4 v = hpre[i];
    unsigned vv[4] = {v.x, v.y, v.z, v.w};
    unsigned o[4];
    float f[8];
#pragma unroll
    for (int j = 0; j < 4; j++) {
      float lo = fmaxf(fmaf(b2f_lo(vv[j]), sc[2 * j], sh[2 * j]), 0.f);
      float hi = fmaxf(fmaf(b2f_hi(vv[j]), sc[2 * j + 1], sh[2 * j + 1]), 0.f);
      f[2 * j] = lo;
      f[2 * j + 1] = hi;
      o[j] = (unsigned)f2b(lo) | ((unsigned)f2b(hi) << 16);
    }
    uint4 ov = {o[0], o[1], o[2], o[3]};
    hout[i] = ov;
    uint2 q;
    q.x = pack_fp8x4(f[0], f[1], f[2], f[3]);
    q.y = pack_fp8x4(f[4], f[5], f[6], f[7]);
    h8out[i] = q;
  }
}

// ---------------- pool stage 1: per-(graph, chunk) BN+ReLU partial sums -----
// grid (64, 8); each block covers 1/8 of its graph's rows; atomic-free.
__global__ __launch_bounds__(256) void pool_partial(
    const u16* __restrict__ hpre, const float* __restrict__ ss,
    const int* __restrict__ batch, float* __restrict__ partial) {
  __shared__ float red[256][9];
  int g = blockIdx.x;
  int i = blockIdx.y;
  int t = threadIdx.x;
  // row range of graph g in sorted batch: [lo, hi)
  int a = 0, b = N_NODES;
  while (a < b) { int m = (a + b) >> 1; if (batch[m] < g) a = m + 1; else b = m; }
  int lo = a;
  b = N_NODES;
  while (a < b) { int m = (a + b) >> 1; if (batch[m] < g + 1) a = m + 1; else b = m; }
  int hi = a;
  int len = hi - lo;
  int clen = (len + 7) >> 3;
  int c0 = lo + i * clen;
  int c1 = min(c0 + clen, hi);

  int rs = t >> 5, cu = t & 31;
  int cb = cu * 8;
  float scv[8], shv[8];
#pragma unroll
  for (int j = 0; j < 8; j++) { scv[j] = ss[cb + j]; shv[j] = ss[HID + cb + j]; }
  float acc[8] = {0.f, 0.f, 0.f, 0.f, 0.f, 0.f, 0.f, 0.f};
  for (int r = c0 + rs; r < c1; r += 8) {
    uint4 v = *((const uint4*)(hpre + (size_t)r * HID) + cu);
    unsigned vv[4] = {v.x, v.y, v.z, v.w};
#pragma unroll
    for (int j = 0; j < 4; j++) {
      acc[2 * j]     += fmaxf(fmaf(b2f_lo(vv[j]), scv[2 * j], shv[2 * j]), 0.f);
      acc[2 * j + 1] += fmaxf(fmaf(b2f_hi(vv[j]), scv[2 * j + 1], shv[2 * j + 1]), 0.f);
    }
  }
#pragma unroll
  for (int j = 0; j < 8; j++) red[t][j] = acc[j];
  __syncthreads();
  // thread t reduces column t across the 8 row-strips
  int cc = t >> 3, j = t & 7;
  float sum = 0.f;
#pragma unroll
  for (int k = 0; k < 8; k++) sum += red[k * 32 + cc][j];
  partial[((size_t)g * 8 + i) * 256 + t] = sum;
}

// ---------------- pool stage 2 + MLP (64 blocks, reads 8 partials/graph) ----
__global__ __launch_bounds__(256) void pool_mlp_final(
    const float* __restrict__ partial, const int* __restrict__ batch,
    const float* __restrict__ W1, const float* __restrict__ b1,
    const float* __restrict__ W2, const float* __restrict__ b2,
    float* __restrict__ out) {
  __shared__ float gs[HID];
  __shared__ float ts[HID];
  __shared__ float rn[PROJ];
  int g = blockIdx.x;
  int t = threadIdx.x;
  // graph length via binary search
  int a = 0, b = N_NODES;
  while (a < b) { int m = (a + b) >> 1; if (batch[m] < g) a = m + 1; else b = m; }
  int lo = a;
  b = N_NODES;
  while (a < b) { int m = (a + b) >> 1; if (batch[m] < g + 1) a = m + 1; else b = m; }
  int len = a - lo;

  float sum = 0.f;
#pragma unroll
  for (int i = 0; i < 8; i++) sum += partial[((size_t)g * 8 + i) * 256 + t];
  float inv = 1.0f / fmaxf((float)len, 1.0f);
  gs[t] = sum * inv;
  __syncthreads();

  float s = b1[t];
  for (int k = 0; k < HID; k++) s = fmaf(gs[k], W1[(size_t)k * HID + t], s);
  ts[t] = fmaxf(s, 0.f);
  __syncthreads();
  float z = 0.f;
  if (t < PROJ) {
    z = b2[t];
    for (int k = 0; k < HID; k++) z = fmaf(ts[k], W2[(size_t)k * PROJ + t], z);
    rn[t] = z * z;
  }
  __syncthreads();
  for (int off = PROJ / 2; off > 0; off >>= 1) {
    if (t < off) rn[t] += rn[t + off];
    __syncthreads();
  }
  float norm = fmaxf(sqrtf(rn[0]), 1e-12f);
  if (t < PROJ) out[(size_t)g * PROJ + t] = z / norm;
}

// --------------------------------------------------------------- launch -----
extern "C" void kernel_launch(void* const* d_in, const int* in_sizes, int n_in,
                              void* d_out, int out_size, void* d_ws, size_t ws_size,
                              hipStream_t stream) {
  const float* x = (const float*)d_in[0];
  const int* ei = (const int*)d_in[1];
  const int* src = ei;
  const int* dst = ei + N_EDGES;
  const int* batch = (const int*)d_in[2];
  const float* Wl = (const float*)d_in[3];
  // d_in[4] = bl: per-column bias is exactly cancelled by BatchNorm -> unused
  const float* Wr = (const float*)d_in[5];
  const float* gamma = (const float*)d_in[6];
  const float* beta = (const float*)d_in[7];
  const float* W1 = (const float*)d_in[8];
  const float* b1 = (const float*)d_in[9];
  const float* W2 = (const float*)d_in[10];
  const float* b2 = (const float*)d_in[11];
  float* out = (float*)d_out;

  char* p = (char*)d_ws;
  const size_t HB = (size_t)M_PAD * HID * sizeof(u16);  // 51.25 MB
  u16* h = (u16*)p;      p += HB;                        // bf16 h / hpre (in-place)
  u16* aggr = (u16*)p;   p += HB;
  unsigned char* h8 = (unsigned char*)p; p += (size_t)M_PAD * HID;  // 25.6 MB fp8
  u16* Wt = (u16*)p;     p += (size_t)NLAYERS * 512 * HID * sizeof(u16);  // 1 MB
  int* col = (int*)p;    p += (size_t)N_EDGES * sizeof(int);              // 6.4 MB
  int* row_ptr = (int*)p; p += 400016;
  float* inv_cnt = (float*)p; p += (size_t)N_NODES * sizeof(float);
  float* psum = (float*)p;    p += (size_t)N_MBLK * 512 * sizeof(float);  // 1.6 MB
  float* tmp = (float*)p;     p += (size_t)BN_MID * 512 * sizeof(float);
  float* ss = (float*)p;      p += 512 * sizeof(float);
  float* partial = (float*)p; p += (size_t)N_GRAPHS * 8 * 256 * sizeof(float);
  uint2* ebuf = (uint2*)p;    p += (size_t)N_BUCKETS * EBUF_STRIDE * sizeof(uint2);  // 25.6 MB

  // transient CSR-build arrays overlaid into aggr (first written in layer-0 agg)
  u64* bfill64 = (u64*)aggr;                       // N_BUCKETS lines (padded x8)
  int* bucket_base = (int*)(bfill64 + (size_t)N_BUCKETS * 8);

  // ---- build CSR (once; edge_index is layer-invariant) ----
  hipMemsetAsync(bfill64, 0, (size_t)N_BUCKETS * 8 * sizeof(u64), stream);
  bucket_scatter<<<CSR_NBLK, CSR_BLK, 0, stream>>>(src, dst, bfill64, ebuf);
  bucket_prefix<<<1, 512, 0, stream>>>(bfill64, bucket_base, row_ptr);
  csr_build<<<N_BUCKETS, CSR_BLK, 0, stream>>>(ebuf, bfill64, bucket_base,
                                               row_ptr, inv_cnt, col);

  // ---- one-time converts ----
  convert_x<<<N_NODES / 4, 256, 0, stream>>>((const float4*)x, (ushort4*)h,
                                             (unsigned*)h8);
  convert_w<<<(NLAYERS * 512 * HID) / 256, 256, 0, stream>>>(Wl, Wr, Wt);

  for (int l = 0; l < NLAYERS; l++) {
    aggregate_fp8<<<N_NODES / 4, 256, 0, stream>>>(h8, row_ptr, col, inv_cnt, aggr);
    gemm_fused<<<N_MBLK, 256, 0, stream>>>(h, aggr, Wt + (size_t)l * 512 * HID,
                                           h, psum);
    bn_mid<<<BN_MID, 256, 0, stream>>>(psum, tmp);
    bn_fin<<<1, 256, 0, stream>>>(tmp, gamma + (size_t)l * HID,
                                  beta + (size_t)l * HID, ss);
    if (l < NLAYERS - 1) {
      bn_apply_fused<<<2048, 256, 0, stream>>>((const uint4*)h, ss, (uint4*)h,
                                               (uint2*)h8);
    }
  }

  // layer-3 BN+ReLU fused into two-stage pooling (reads h(=hpre) + ss)
  pool_partial<<<dim3(N_GRAPHS, 8), 256, 0, stream>>>(h, ss, batch, partial);
  pool_mlp_final<<<N_GRAPHS, 256, 0, stream>>>(partial, batch, W1, b1, W2, b2, out);
}

// Round 5
// 783.582 us; speedup vs baseline: 1.8943x; 1.0838x over previous
//
#include <hip/hip_runtime.h>

#define N_NODES 100000
#define M_PAD   100096   // 782 * 128
#define N_MBLK  782
#define N_EDGES 1600000
#define N_GRAPHS 64
#define HID 256
#define PROJ 128
#define NLAYERS 4

#define EBUF_STRIDE 8192
#define N_BUCKETS ((N_NODES + 255) / 256)  // 391
#define CSR_BLK 1024
#define EPT 10
#define CSR_NBLK ((N_EDGES + CSR_BLK * EPT - 1) / (CSR_BLK * EPT))  // 157
#define SENT 0xFFFFFFFFu

typedef unsigned short u16;
typedef unsigned long long u64;
typedef __attribute__((ext_vector_type(4))) float f32x4;
typedef __attribute__((ext_vector_type(2))) float vf2;

__device__ __forceinline__ float b2f_lo(unsigned u) {
  return __uint_as_float(u << 16);
}
__device__ __forceinline__ float b2f_hi(unsigned u) {
  return __uint_as_float(u & 0xFFFF0000u);
}
__device__ __forceinline__ u16 f2b(float f) {
  unsigned u = __float_as_uint(f);
  u = (u + 0x7FFF + ((u >> 16) & 1)) >> 16;  // round-to-nearest-even
  return (u16)u;
}
__device__ __forceinline__ void gload16(const void* g, void* l) {
  __builtin_amdgcn_global_load_lds((const __attribute__((address_space(1))) void*)g,
                                   (__attribute__((address_space(3))) void*)l, 16, 0, 0);
}
// ---- fp8 e4m3 (HW cvt; encode/decode self-consistent) ----
__device__ __forceinline__ unsigned pack_fp8x4(float a, float b, float c, float d) {
  int v = __builtin_amdgcn_cvt_pk_fp8_f32(a, b, 0, false);
  v = __builtin_amdgcn_cvt_pk_fp8_f32(c, d, v, true);
  return (unsigned)v;
}
__device__ __forceinline__ void accf8(float* a, unsigned w) {
  vf2 lo = __builtin_amdgcn_cvt_pk_f32_fp8((int)w, false);
  vf2 hi = __builtin_amdgcn_cvt_pk_f32_fp8((int)w, true);
  a[0] += lo.x; a[1] += lo.y; a[2] += hi.x; a[3] += hi.y;
}

// ---------------------------------------------------------------- CSR -------
// Pass A: bucket scatter (no per-node count atomics). Per-(block,bucket) runs
// reserved 64B-line aligned via ONE packed 64-bit atomic (alloc<<32 | valid);
// pad slots get sentinels from the owning block -> one writer per ebuf line.
__global__ __launch_bounds__(1024) void bucket_scatter(
    const int* __restrict__ src, const int* __restrict__ dst,
    u64* __restrict__ bfill64, uint2* __restrict__ ebuf) {
  __shared__ int lhist[N_BUCKETS];
  __shared__ int lbase[N_BUCKETS];
  int t = threadIdx.x;
  int e0 = blockIdx.x * (CSR_BLK * EPT) + t;
  for (int i = t; i < N_BUCKETS; i += CSR_BLK) lhist[i] = 0;
  __syncthreads();
  int sv[EPT], dv[EPT];
#pragma unroll
  for (int j = 0; j < EPT; j++) {
    int e = e0 + j * CSR_BLK;
    if (e < N_EDGES) {
      sv[j] = src[e];
      dv[j] = dst[e];
      atomicAdd(&lhist[dv[j] >> 8], 1);
    } else {
      dv[j] = -1;
      sv[j] = 0;
    }
  }
  __syncthreads();
  for (int i = t; i < N_BUCKETS; i += CSR_BLK) {
    int c = lhist[i];
    if (c > 0) {
      int rounded = (c + 7) & ~7;  // 8 slots = 64B line alignment
      u64 old = atomicAdd(&bfill64[(size_t)i * 8],
                          ((u64)rounded << 32) | (u64)c);
      int base = (int)(old >> 32);
      lbase[i] = base;
      for (int k = c; k < rounded; k++) {  // self-write pad sentinels
        int p = base + k;
        if (p < EBUF_STRIDE) {
          uint2 q; q.x = 0; q.y = SENT;
          ebuf[(size_t)i * EBUF_STRIDE + p] = q;
        }
      }
      lhist[i] = 0;  // reuse as block-local fill cursor
    }
  }
  __syncthreads();
#pragma unroll
  for (int j = 0; j < EPT; j++) {
    if (dv[j] >= 0) {
      int b = dv[j] >> 8;
      int p = lbase[b] + atomicAdd(&lhist[b], 1);
      if (p < EBUF_STRIDE) {  // ~47-sigma margin; drop-safe guard
        uint2 q;
        q.x = (unsigned)sv[j];
        q.y = (unsigned)dv[j];
        ebuf[(size_t)b * EBUF_STRIDE + p] = q;
      }
    }
  }
}

// Pass A1: scan 391 per-bucket valid counts -> bucket bases + total.
__global__ __launch_bounds__(512) void bucket_prefix(
    const u64* __restrict__ bfill64, int* __restrict__ bucket_base,
    int* __restrict__ row_ptr) {
  __shared__ int tile[512];
  int t = threadIdx.x;
  int v = 0;
  if (t < N_BUCKETS) {
    u64 w = bfill64[(size_t)t * 8];
    v = (int)(w & 0xFFFFFFFFull);
    if ((int)(w >> 32) > EBUF_STRIDE) v = min(v, EBUF_STRIDE);  // degenerate clamp
  }
  tile[t] = v;
  __syncthreads();
  for (int off = 1; off < 512; off <<= 1) {
    int add = (t >= off) ? tile[t - off] : 0;
    __syncthreads();
    tile[t] += add;
    __syncthreads();
  }
  if (t < N_BUCKETS) bucket_base[t] = tile[t] - v;  // exclusive
  if (t == N_BUCKETS - 1) row_ptr[N_NODES] = tile[t];
}

// Pass B: one block per bucket; LDS-only atomics; col writes land in a ~16KB
// single-CU window.
__global__ __launch_bounds__(1024) void csr_build(
    const uint2* __restrict__ ebuf, const u64* __restrict__ bfill64,
    const int* __restrict__ bucket_base, int* __restrict__ row_ptr,
    float* __restrict__ inv_cnt, int* __restrict__ col) {
  __shared__ int hist[256];
  __shared__ int nscan[256];
  __shared__ int cursor[256];
  int b = blockIdx.x;
  int t = threadIdx.x;
  int nalloc = min((int)(bfill64[(size_t)b * 8] >> 32), EBUF_STRIDE);
  int bbase = bucket_base[b];
  if (t < 256) hist[t] = 0;
  __syncthreads();
  uint2 q[8];
#pragma unroll
  for (int k = 0; k < 8; k++) {
    int i = t + k * CSR_BLK;
    q[k].x = 0; q[k].y = SENT;
    if (i < nalloc) {
      q[k] = ebuf[(size_t)b * EBUF_STRIDE + i];
      if (q[k].y != SENT) atomicAdd(&hist[q[k].y & 255], 1);
    }
  }
  __syncthreads();
  if (t < 256) nscan[t] = hist[t];
  __syncthreads();
  for (int off = 1; off < 256; off <<= 1) {
    int add = 0;
    if (t < 256 && t >= off) add = nscan[t - off];
    __syncthreads();
    if (t < 256) nscan[t] += add;
    __syncthreads();
  }
  int nb = min(256, N_NODES - b * 256);
  if (t < 256) {
    int excl = nscan[t] - hist[t];
    cursor[t] = excl;
    if (t < nb) {
      row_ptr[b * 256 + t] = bbase + excl;
      inv_cnt[b * 256 + t] = 1.0f / fmaxf((float)hist[t], 1.0f);
    }
  }
  __syncthreads();
#pragma unroll
  for (int k = 0; k < 8; k++) {
    if (q[k].y != SENT) {
      int l = (int)(q[k].y & 255);
      int pos = bbase + atomicAdd(&cursor[l], 1);
      col[pos] = (int)q[k].x;
    }
  }
}

// ------------------------------------------------------------ converts ------
// x -> fp8 shadow only (bf16 h buffer eliminated; GEMM is now fp8 too)
__global__ __launch_bounds__(256) void convert_x8(const float4* __restrict__ x,
                                                  unsigned* __restrict__ h8) {
  int i = blockIdx.x * blockDim.x + threadIdx.x;  // exactly N_NODES*64 threads
  float4 v = x[i];
  h8[i] = pack_fp8x4(v.x, v.y, v.z, v.w);
}

// Wt8[l][n][k] fp8: k<256 -> Wl[l][k][n], k>=256 -> Wr[l][k-256][n]
__global__ __launch_bounds__(256) void convert_w8(const float* __restrict__ Wl,
                                                  const float* __restrict__ Wr,
                                                  unsigned* __restrict__ Wt8) {
  int idx = blockIdx.x * blockDim.x + threadIdx.x;  // NLAYERS*512*HID/4 threads
  int l = idx >> 15;
  int r = idx & 32767;
  int n = r >> 7;
  int k4 = (r & 127) * 4;
  float v[4];
#pragma unroll
  for (int j = 0; j < 4; j++) {
    int k = k4 + j;
    v[j] = (k < 256) ? Wl[(size_t)l * 65536 + k * 256 + n]
                     : Wr[(size_t)l * 65536 + (k - 256) * 256 + n];
  }
  Wt8[idx] = pack_fp8x4(v[0], v[1], v[2], v[3]);
}

// ----------------------------------------------------------- aggregation ----
// one wave per node; two 32-lane halves process alternating edges with 8B fp8
// loads; output now fp8 too (half the write traffic; feeds fp8 GEMM).
__global__ __launch_bounds__(256) void aggregate_fp8(
    const unsigned char* __restrict__ h8, const int* __restrict__ row_ptr,
    const int* __restrict__ col, const float* __restrict__ inv_cnt,
    unsigned char* __restrict__ aggr8) {
  int node = blockIdx.x * 4 + (threadIdx.x >> 6);
  int lane = threadIdx.x & 63;
  int half = lane >> 5, l32 = lane & 31;
  int r0 = row_ptr[node], r1 = row_ptr[node + 1];
  float a[8] = {0.f, 0.f, 0.f, 0.f, 0.f, 0.f, 0.f, 0.f};
  int e = r0 + half;
  for (; e + 14 < r1; e += 16) {
    int s[8];
#pragma unroll
    for (int j = 0; j < 8; j++) s[j] = col[e + 2 * j];
    uint2 v[8];
#pragma unroll
    for (int j = 0; j < 8; j++)
      v[j] = *((const uint2*)(h8 + (size_t)s[j] * HID) + l32);
#pragma unroll
    for (int j = 0; j < 8; j++) { accf8(a, v[j].x); accf8(a + 4, v[j].y); }
  }
  for (; e + 6 < r1; e += 8) {
    int s0 = col[e], s1 = col[e + 2], s2 = col[e + 4], s3 = col[e + 6];
    uint2 v0 = *((const uint2*)(h8 + (size_t)s0 * HID) + l32);
    uint2 v1 = *((const uint2*)(h8 + (size_t)s1 * HID) + l32);
    uint2 v2 = *((const uint2*)(h8 + (size_t)s2 * HID) + l32);
    uint2 v3 = *((const uint2*)(h8 + (size_t)s3 * HID) + l32);
    accf8(a, v0.x); accf8(a + 4, v0.y);
    accf8(a, v1.x); accf8(a + 4, v1.y);
    accf8(a, v2.x); accf8(a + 4, v2.y);
    accf8(a, v3.x); accf8(a + 4, v3.y);
  }
  for (; e < r1; e += 2) {
    int s0 = col[e];
    uint2 v0 = *((const uint2*)(h8 + (size_t)s0 * HID) + l32);
    accf8(a, v0.x); accf8(a + 4, v0.y);
  }
#pragma unroll
  for (int j = 0; j < 8; j++) a[j] += __shfl_xor(a[j], 32, 64);
  if (half == 0) {
    float inv = inv_cnt[node];
    uint2 o;
    o.x = pack_fp8x4(a[0] * inv, a[1] * inv, a[2] * inv, a[3] * inv);
    o.y = pack_fp8x4(a[4] * inv, a[5] * inv, a[6] * inv, a[7] * inv);
    *((uint2*)(aggr8 + (size_t)node * HID) + l32) = o;
  }
}

// ------------------------------- fp8 MFMA GEMM + fused BN partials ----------
// hpre[m][n] = sum_k cat(aggr8,h8)[m][k] * B[k][n];  B^T given as Wt8[n][k].
// 128x256 tile, BK=64 fp8 (rows are 64B -- byte-identical staging geometry to
// the old BK=32 bf16 scheme). mfma_f32_16x16x32_fp8_fp8 runs at bf16 rate with
// half the operand bytes; staging traffic halves.
__global__ __launch_bounds__(256, 2) void gemm_fused_fp8(
    const unsigned char* __restrict__ a8, const unsigned char* __restrict__ h8,
    const unsigned char* __restrict__ Bt8, u16* __restrict__ hpre,
    float* __restrict__ psum) {
  __shared__ unsigned char smem[128 * 64 + 256 * 64];  // 24 KB; reused as epilogue buf
  __shared__ float bns[4][8][16][2];                   // 4 KB
  unsigned char* As = smem;
  unsigned char* Bs = smem + 128 * 64;
  u16* ep = (u16*)smem;  // 32 rows x 256 cols bf16 = 16 KB (after final K sync)

  int tid = threadIdx.x;
  int wid = tid >> 6, lane = tid & 63;
  int m0 = blockIdx.x * 128;
  int q = lane >> 4, c = lane & 15;
  int wm = (wid >> 1) * 64, wn = (wid & 1) * 128;

  f32x4 zero = {0.f, 0.f, 0.f, 0.f};
  f32x4 acc[4][8];
#pragma unroll
  for (int mi = 0; mi < 4; mi++)
#pragma unroll
    for (int ni = 0; ni < 8; ni++) acc[mi][ni] = zero;

  // A staging geometry (2 issues/thread); 16B chunk = 16 fp8 k-elems
  int srowA0 = wid * 32 + (lane >> 2);
  int cgA0 = (lane & 3) ^ ((srowA0 >> 1) & 3);
  int srowA1 = srowA0 + 16;
  int cgA1 = (lane & 3) ^ ((srowA1 >> 1) & 3);
  // B staging geometry (4 issues/thread)
  int srowB[4], cgB[4];
#pragma unroll
  for (int j = 0; j < 4; j++) {
    srowB[j] = j * 64 + wid * 16 + (lane >> 2);
    cgB[j] = (lane & 3) ^ ((srowB[j] >> 1) & 3);
  }

  // frag-read LDS byte offsets: per mi/ni and per kk (K=32 half of BK=64)
  int aoff[4][2], boff[8][2];
#pragma unroll
  for (int mi = 0; mi < 4; mi++) {
    int row = wm + mi * 16 + c;
    int x = (row >> 1) & 3;
#pragma unroll
    for (int kk = 0; kk < 2; kk++) {
      int chunk = kk * 2 + (q >> 1);
      aoff[mi][kk] = row * 64 + ((chunk ^ x) << 4) + ((q & 1) << 3);
    }
  }
#pragma unroll
  for (int ni = 0; ni < 8; ni++) {
    int row = wn + ni * 16 + c;
    int x = (row >> 1) & 3;
#pragma unroll
    for (int kk = 0; kk < 2; kk++) {
      int chunk = kk * 2 + (q >> 1);
      boff[ni][kk] = row * 64 + ((chunk ^ x) << 4) + ((q & 1) << 3);
    }
  }

  for (int k0 = 0; k0 < 512; k0 += 64) {
    const unsigned char* Asrc = (k0 < 256) ? a8 : h8;
    int ksrc = k0 & 255;
    gload16(Asrc + ((size_t)(m0 + srowA0) * HID + ksrc + cgA0 * 16), &As[(wid * 32) * 64]);
    gload16(Asrc + ((size_t)(m0 + srowA1) * HID + ksrc + cgA1 * 16), &As[(wid * 32 + 16) * 64]);
#pragma unroll
    for (int j = 0; j < 4; j++)
      gload16(Bt8 + ((size_t)srowB[j] * 512 + k0 + cgB[j] * 16), &Bs[(j * 64 + wid * 16) * 64]);
    __syncthreads();
    long long af[4][2], bfr[8][2];
#pragma unroll
    for (int mi = 0; mi < 4; mi++) {
      af[mi][0] = *(const long long*)&As[aoff[mi][0]];
      af[mi][1] = *(const long long*)&As[aoff[mi][1]];
    }
#pragma unroll
    for (int ni = 0; ni < 8; ni++) {
      bfr[ni][0] = *(const long long*)&Bs[boff[ni][0]];
      bfr[ni][1] = *(const long long*)&Bs[boff[ni][1]];
    }
#pragma unroll
    for (int mi = 0; mi < 4; mi++)
#pragma unroll
      for (int ni = 0; ni < 8; ni++) {
        acc[mi][ni] = __builtin_amdgcn_mfma_f32_16x16x32_fp8_fp8(
            af[mi][0], bfr[ni][0], acc[mi][ni], 0, 0, 0);
        acc[mi][ni] = __builtin_amdgcn_mfma_f32_16x16x32_fp8_fp8(
            af[mi][1], bfr[ni][1], acc[mi][ni], 0, 0, 0);
      }
    __syncthreads();
  }

  // ---- coalesced C-store: 4 slabs of 32 rows via LDS transpose ----
  int rh = wid >> 1;  // row half (0: rows 0-63, 1: rows 64-127)
#pragma unroll
  for (int mi = 0; mi < 4; mi++) {
#pragma unroll
    for (int r = 0; r < 4; r++) {
      int r16 = q * 4 + r;
#pragma unroll
      for (int ni = 0; ni < 8; ni++)
        ep[(rh * 16 + r16) * 256 + wn + ni * 16 + c] = f2b(acc[mi][ni][r]);
    }
    __syncthreads();
    int u = tid;
#pragma unroll
    for (int j = 0; j < 4; j++, u += 256) {
      int lr = u >> 5;     // 0..31 local row
      int cu = u & 31;     // uint4 column
      int gm = m0 + (lr >> 4) * 64 + mi * 16 + (lr & 15);
      if (gm < N_NODES)
        ((uint4*)(hpre + (size_t)gm * HID))[cu] = ((const uint4*)ep)[u];
    }
    __syncthreads();
  }

  // ---- BN column partials from fp32 acc (mask pad rows) ----
#pragma unroll
  for (int ni = 0; ni < 8; ni++) {
    float s = 0.f, s2 = 0.f;
#pragma unroll
    for (int mi = 0; mi < 4; mi++) {
#pragma unroll
      for (int r = 0; r < 4; r++) {
        int gm = m0 + wm + mi * 16 + q * 4 + r;
        float v = (gm < N_NODES) ? acc[mi][ni][r] : 0.f;
        s += v;
        s2 += v * v;
      }
    }
    s += __shfl_xor(s, 16, 64);
    s += __shfl_xor(s, 32, 64);
    s2 += __shfl_xor(s2, 16, 64);
    s2 += __shfl_xor(s2, 32, 64);
    if (q == 0) {
      bns[wid][ni][c][0] = s;
      bns[wid][ni][c][1] = s2;
    }
  }
  __syncthreads();
  {
    int wnh = tid >> 7, ni = (tid >> 4) & 7, cc = tid & 15;
    float s = bns[wnh][ni][cc][0] + bns[wnh + 2][ni][cc][0];
    float s2 = bns[wnh][ni][cc][1] + bns[wnh + 2][ni][cc][1];
    int coln = wnh * 128 + ni * 16 + cc;
    psum[(size_t)blockIdx.x * 512 + coln] = s;
    psum[(size_t)blockIdx.x * 512 + 256 + coln] = s2;
  }
}

// --------------------------------- BN reduce (tree, atomic-free) ------------
#define BN_MID 16
__global__ __launch_bounds__(256) void bn_mid(const float* __restrict__ psum,
                                              float* __restrict__ tmp) {
  int b = blockIdx.x;
  int f = threadIdx.x;
  int mb0 = b * 49;
  int mb1 = min(mb0 + 49, N_MBLK);
  float s = 0.f, s2 = 0.f;
  for (int mb = mb0; mb < mb1; mb++) {
    s += psum[(size_t)mb * 512 + f];
    s2 += psum[(size_t)mb * 512 + 256 + f];
  }
  tmp[(size_t)b * 512 + f] = s;
  tmp[(size_t)b * 512 + 256 + f] = s2;
}

__global__ void bn_fin(const float* __restrict__ tmp,
                       const float* __restrict__ gamma,
                       const float* __restrict__ beta,
                       float* __restrict__ ss) {
  int f = threadIdx.x;
  float sum = 0.f, sq = 0.f;
#pragma unroll
  for (int b = 0; b < BN_MID; b++) {
    sum += tmp[(size_t)b * 512 + f];
    sq += tmp[(size_t)b * 512 + 256 + f];
  }
  const float invN = 1.0f / (float)N_NODES;
  float mu = sum * invN;
  float ex2 = sq * invN;
  float var = fmaxf(ex2 - mu * mu, 0.f);
  float sc = gamma[f] * rsqrtf(var + 1e-5f);
  ss[f] = sc;
  ss[HID + f] = beta[f] - mu * sc;
}

// BN+ReLU apply: reads bf16 hpre, writes ONLY the fp8 shadow (the bf16 h
// buffer is gone -- both downstream consumers read fp8).
__global__ __launch_bounds__(256) void bn_apply_h8(const uint4* __restrict__ hpre,
                                                   const float* __restrict__ ss,
                                                   uint2* __restrict__ h8out) {
  int idx0 = blockIdx.x * blockDim.x + threadIdx.x;
  int cb = (idx0 & 31) * 8;  // column base (row = 32 uint4)
  float sc[8], sh[8];
#pragma unroll
  for (int j = 0; j < 8; j++) { sc[j] = ss[cb + j]; sh[j] = ss[HID + cb + j]; }
  const int total = N_NODES * 32;
  const int step = gridDim.x * blockDim.x;  // 524288, multiple of 32
  for (int i = idx0; i < total; i += step) {
    uint4 v = hpre[i];
    unsigned vv[4] = {v.x, v.y, v.z, v.w};
    float f[8];
#pragma unroll
    for (int j = 0; j < 4; j++) {
      f[2 * j]     = fmaxf(fmaf(b2f_lo(vv[j]), sc[2 * j], sh[2 * j]), 0.f);
      f[2 * j + 1] = fmaxf(fmaf(b2f_hi(vv[j]), sc[2 * j + 1], sh[2 * j + 1]), 0.f);
    }
    uint2 q;
    q.x = pack_fp8x4(f[0], f[1], f[2], f[3]);
    q.y = pack_fp8x4(f[4], f[5], f[6], f[7]);
    h8out[i] = q;
  }
}

// ---------------- pool stage 1: per-(graph, chunk) BN+ReLU partial sums -----
__global__ __launch_bounds__(256) void pool_partial(
    const u16* __restrict__ hpre, const float* __restrict__ ss,
    const int* __restrict__ batch, float* __restrict__ partial) {
  __shared__ float red[256][9];
  int g = blockIdx.x;
  int i = blockIdx.y;
  int t = threadIdx.x;
  int a = 0, b = N_NODES;
  while (a < b) { int m = (a + b) >> 1; if (batch[m] < g) a = m + 1; else b = m; }
  int lo = a;
  b = N_NODES;
  while (a < b) { int m = (a + b) >> 1; if (batch[m] < g + 1) a = m + 1; else b = m; }
  int hi = a;
  int len = hi - lo;
  int clen = (len + 7) >> 3;
  int c0 = lo + i * clen;
  int c1 = min(c0 + clen, hi);

  int rs = t >> 5, cu = t & 31;
  int cb = cu * 8;
  float scv[8], shv[8];
#pragma unroll
  for (int j = 0; j < 8; j++) { scv[j] = ss[cb + j]; shv[j] = ss[HID + cb + j]; }
  float acc[8] = {0.f, 0.f, 0.f, 0.f, 0.f, 0.f, 0.f, 0.f};
  for (int r = c0 + rs; r < c1; r += 8) {
    uint4 v = *((const uint4*)(hpre + (size_t)r * HID) + cu);
    unsigned vv[4] = {v.x, v.y, v.z, v.w};
#pragma unroll
    for (int j = 0; j < 4; j++) {
      acc[2 * j]     += fmaxf(fmaf(b2f_lo(vv[j]), scv[2 * j], shv[2 * j]), 0.f);
      acc[2 * j + 1] += fmaxf(fmaf(b2f_hi(vv[j]), scv[2 * j + 1], shv[2 * j + 1]), 0.f);
    }
  }
#pragma unroll
  for (int j = 0; j < 8; j++) red[t][j] = acc[j];
  __syncthreads();
  int cc = t >> 3, j = t & 7;
  float sum = 0.f;
#pragma unroll
  for (int k = 0; k < 8; k++) sum += red[k * 32 + cc][j];
  partial[((size_t)g * 8 + i) * 256 + t] = sum;
}

// ---------------- pool stage 2 + MLP (64 blocks, reads 8 partials/graph) ----
__global__ __launch_bounds__(256) void pool_mlp_final(
    const float* __restrict__ partial, const int* __restrict__ batch,
    const float* __restrict__ W1, const float* __restrict__ b1,
    const float* __restrict__ W2, const float* __restrict__ b2,
    float* __restrict__ out) {
  __shared__ float gs[HID];
  __shared__ float ts[HID];
  __shared__ float rn[PROJ];
  int g = blockIdx.x;
  int t = threadIdx.x;
  int a = 0, b = N_NODES;
  while (a < b) { int m = (a + b) >> 1; if (batch[m] < g) a = m + 1; else b = m; }
  int lo = a;
  b = N_NODES;
  while (a < b) { int m = (a + b) >> 1; if (batch[m] < g + 1) a = m + 1; else b = m; }
  int len = a - lo;

  float sum = 0.f;
#pragma unroll
  for (int i = 0; i < 8; i++) sum += partial[((size_t)g * 8 + i) * 256 + t];
  float inv = 1.0f / fmaxf((float)len, 1.0f);
  gs[t] = sum * inv;
  __syncthreads();

  float s = b1[t];
  for (int k = 0; k < HID; k++) s = fmaf(gs[k], W1[(size_t)k * HID + t], s);
  ts[t] = fmaxf(s, 0.f);
  __syncthreads();
  float z = 0.f;
  if (t < PROJ) {
    z = b2[t];
    for (int k = 0; k < HID; k++) z = fmaf(ts[k], W2[(size_t)k * PROJ + t], z);
    rn[t] = z * z;
  }
  __syncthreads();
  for (int off = PROJ / 2; off > 0; off >>= 1) {
    if (t < off) rn[t] += rn[t + off];
    __syncthreads();
  }
  float norm = fmaxf(sqrtf(rn[0]), 1e-12f);
  if (t < PROJ) out[(size_t)g * PROJ + t] = z / norm;
}

// --------------------------------------------------------------- launch -----
extern "C" void kernel_launch(void* const* d_in, const int* in_sizes, int n_in,
                              void* d_out, int out_size, void* d_ws, size_t ws_size,
                              hipStream_t stream) {
  const float* x = (const float*)d_in[0];
  const int* ei = (const int*)d_in[1];
  const int* src = ei;
  const int* dst = ei + N_EDGES;
  const int* batch = (const int*)d_in[2];
  const float* Wl = (const float*)d_in[3];
  // d_in[4] = bl: per-column bias is exactly cancelled by BatchNorm -> unused
  const float* Wr = (const float*)d_in[5];
  const float* gamma = (const float*)d_in[6];
  const float* beta = (const float*)d_in[7];
  const float* W1 = (const float*)d_in[8];
  const float* b1 = (const float*)d_in[9];
  const float* W2 = (const float*)d_in[10];
  const float* b2 = (const float*)d_in[11];
  float* out = (float*)d_out;

  char* p = (char*)d_ws;
  const size_t HB = (size_t)M_PAD * HID * sizeof(u16);   // 51.25 MB
  const size_t H8 = (size_t)M_PAD * HID;                 // 25.6 MB
  u16* hpre = (u16*)p;   p += HB;   // bf16 pre-BN activations (BN/pool input)
  unsigned char* aggr8 = (unsigned char*)p; p += H8;
  unsigned char* h8 = (unsigned char*)p;    p += H8;
  unsigned char* Wt8 = (unsigned char*)p;   p += (size_t)NLAYERS * 512 * HID;  // 0.5 MB
  int* col = (int*)p;    p += (size_t)N_EDGES * sizeof(int);              // 6.4 MB
  int* row_ptr = (int*)p; p += 400016;
  float* inv_cnt = (float*)p; p += (size_t)N_NODES * sizeof(float);
  float* psum = (float*)p;    p += (size_t)N_MBLK * 512 * sizeof(float);  // 1.6 MB
  float* tmp = (float*)p;     p += (size_t)BN_MID * 512 * sizeof(float);
  float* ss = (float*)p;      p += 512 * sizeof(float);
  float* partial = (float*)p; p += (size_t)N_GRAPHS * 8 * 256 * sizeof(float);
  uint2* ebuf = (uint2*)p;    p += (size_t)N_BUCKETS * EBUF_STRIDE * sizeof(uint2);  // 25.6 MB

  // transient CSR-build arrays overlaid into hpre (first written in layer-0 gemm,
  // which is stream-ordered after csr_build completes)
  u64* bfill64 = (u64*)hpre;                       // N_BUCKETS lines (padded x8)
  int* bucket_base = (int*)(bfill64 + (size_t)N_BUCKETS * 8);

  // ---- build CSR (once; edge_index is layer-invariant) ----
  hipMemsetAsync(bfill64, 0, (size_t)N_BUCKETS * 8 * sizeof(u64), stream);
  bucket_scatter<<<CSR_NBLK, CSR_BLK, 0, stream>>>(src, dst, bfill64, ebuf);
  bucket_prefix<<<1, 512, 0, stream>>>(bfill64, bucket_base, row_ptr);
  csr_build<<<N_BUCKETS, CSR_BLK, 0, stream>>>(ebuf, bfill64, bucket_base,
                                               row_ptr, inv_cnt, col);

  // ---- one-time converts ----
  convert_x8<<<N_NODES / 4, 256, 0, stream>>>((const float4*)x, (unsigned*)h8);
  convert_w8<<<(NLAYERS * 512 * HID / 4) / 256, 256, 0, stream>>>(Wl, Wr,
                                                                  (unsigned*)Wt8);

  for (int l = 0; l < NLAYERS; l++) {
    aggregate_fp8<<<N_NODES / 4, 256, 0, stream>>>(h8, row_ptr, col, inv_cnt, aggr8);
    gemm_fused_fp8<<<N_MBLK, 256, 0, stream>>>(aggr8, h8,
                                               Wt8 + (size_t)l * 512 * HID,
                                               hpre, psum);
    bn_mid<<<BN_MID, 256, 0, stream>>>(psum, tmp);
    bn_fin<<<1, 256, 0, stream>>>(tmp, gamma + (size_t)l * HID,
                                  beta + (size_t)l * HID, ss);
    if (l < NLAYERS - 1) {
      bn_apply_h8<<<2048, 256, 0, stream>>>((const uint4*)hpre, ss, (uint2*)h8);
    }
  }

  // layer-3 BN+ReLU fused into two-stage pooling (reads hpre + ss)
  pool_partial<<<dim3(N_GRAPHS, 8), 256, 0, stream>>>(hpre, ss, batch, partial);
  pool_mlp_final<<<N_GRAPHS, 256, 0, stream>>>(partial, batch, W1, b1, W2, b2, out);
}

// Round 6
// 770.810 us; speedup vs baseline: 1.9257x; 1.0166x over previous
//
#include <hip/hip_runtime.h>

#define N_NODES 100000
#define M_PAD   100096   // 782 * 128
#define N_MBLK  782
#define N_EDGES 1600000
#define N_GRAPHS 64
#define HID 256
#define PROJ 128
#define NLAYERS 4

#define EBUF_STRIDE 8192
#define N_BUCKETS ((N_NODES + 255) / 256)  // 391
#define CSR_BLK 1024
#define EPT 10
#define CSR_NBLK ((N_EDGES + CSR_BLK * EPT - 1) / (CSR_BLK * EPT))  // 157
#define SENT 0xFFFFFFFFu
#define GEMM_BUF 24576  // one LDS buffer: A 128x64 + B 256x64 fp8

typedef unsigned short u16;
typedef unsigned long long u64;
typedef __attribute__((ext_vector_type(4))) float f32x4;
typedef __attribute__((ext_vector_type(2))) float vf2;

__device__ __forceinline__ u16 f2b(float f) {
  unsigned u = __float_as_uint(f);
  u = (u + 0x7FFF + ((u >> 16) & 1)) >> 16;  // round-to-nearest-even
  return (u16)u;
}
__device__ __forceinline__ void gload16(const void* g, void* l) {
  __builtin_amdgcn_global_load_lds((const __attribute__((address_space(1))) void*)g,
                                   (__attribute__((address_space(3))) void*)l, 16, 0, 0);
}
// ---- fp8 e4m3 (HW cvt; encode/decode self-consistent) ----
__device__ __forceinline__ unsigned pack_fp8x4(float a, float b, float c, float d) {
  int v = __builtin_amdgcn_cvt_pk_fp8_f32(a, b, 0, false);
  v = __builtin_amdgcn_cvt_pk_fp8_f32(c, d, v, true);
  return (unsigned)v;
}
__device__ __forceinline__ unsigned char f2f8(float a) {
  return (unsigned char)(__builtin_amdgcn_cvt_pk_fp8_f32(a, a, 0, false) & 0xFF);
}
__device__ __forceinline__ void accf8(float* a, unsigned w) {
  vf2 lo = __builtin_amdgcn_cvt_pk_f32_fp8((int)w, false);
  vf2 hi = __builtin_amdgcn_cvt_pk_f32_fp8((int)w, true);
  a[0] += lo.x; a[1] += lo.y; a[2] += hi.x; a[3] += hi.y;
}
__device__ __forceinline__ void decf8(float* f, unsigned w) {
  vf2 lo = __builtin_amdgcn_cvt_pk_f32_fp8((int)w, false);
  vf2 hi = __builtin_amdgcn_cvt_pk_f32_fp8((int)w, true);
  f[0] = lo.x; f[1] = lo.y; f[2] = hi.x; f[3] = hi.y;
}

// ---------------------------------------------------------------- CSR -------
// Pass A: bucket scatter (no per-node count atomics). Per-(block,bucket) runs
// reserved 64B-line aligned via ONE packed 64-bit atomic (alloc<<32 | valid);
// pad slots get sentinels from the owning block -> one writer per ebuf line.
__global__ __launch_bounds__(1024) void bucket_scatter(
    const int* __restrict__ src, const int* __restrict__ dst,
    u64* __restrict__ bfill64, uint2* __restrict__ ebuf) {
  __shared__ int lhist[N_BUCKETS];
  __shared__ int lbase[N_BUCKETS];
  int t = threadIdx.x;
  int e0 = blockIdx.x * (CSR_BLK * EPT) + t;
  for (int i = t; i < N_BUCKETS; i += CSR_BLK) lhist[i] = 0;
  __syncthreads();
  int sv[EPT], dv[EPT];
#pragma unroll
  for (int j = 0; j < EPT; j++) {
    int e = e0 + j * CSR_BLK;
    if (e < N_EDGES) {
      sv[j] = src[e];
      dv[j] = dst[e];
      atomicAdd(&lhist[dv[j] >> 8], 1);
    } else {
      dv[j] = -1;
      sv[j] = 0;
    }
  }
  __syncthreads();
  for (int i = t; i < N_BUCKETS; i += CSR_BLK) {
    int c = lhist[i];
    if (c > 0) {
      int rounded = (c + 7) & ~7;  // 8 slots = 64B line alignment
      u64 old = atomicAdd(&bfill64[(size_t)i * 8],
                          ((u64)rounded << 32) | (u64)c);
      int base = (int)(old >> 32);
      lbase[i] = base;
      for (int k = c; k < rounded; k++) {  // self-write pad sentinels
        int p = base + k;
        if (p < EBUF_STRIDE) {
          uint2 q; q.x = 0; q.y = SENT;
          ebuf[(size_t)i * EBUF_STRIDE + p] = q;
        }
      }
      lhist[i] = 0;  // reuse as block-local fill cursor
    }
  }
  __syncthreads();
#pragma unroll
  for (int j = 0; j < EPT; j++) {
    if (dv[j] >= 0) {
      int b = dv[j] >> 8;
      int p = lbase[b] + atomicAdd(&lhist[b], 1);
      if (p < EBUF_STRIDE) {  // ~47-sigma margin; drop-safe guard
        uint2 q;
        q.x = (unsigned)sv[j];
        q.y = (unsigned)dv[j];
        ebuf[(size_t)b * EBUF_STRIDE + p] = q;
      }
    }
  }
}

// Pass A1: scan 391 per-bucket valid counts -> bucket bases + total.
__global__ __launch_bounds__(512) void bucket_prefix(
    const u64* __restrict__ bfill64, int* __restrict__ bucket_base,
    int* __restrict__ row_ptr) {
  __shared__ int tile[512];
  int t = threadIdx.x;
  int v = 0;
  if (t < N_BUCKETS) {
    u64 w = bfill64[(size_t)t * 8];
    v = (int)(w & 0xFFFFFFFFull);
    if ((int)(w >> 32) > EBUF_STRIDE) v = min(v, EBUF_STRIDE);  // degenerate clamp
  }
  tile[t] = v;
  __syncthreads();
  for (int off = 1; off < 512; off <<= 1) {
    int add = (t >= off) ? tile[t - off] : 0;
    __syncthreads();
    tile[t] += add;
    __syncthreads();
  }
  if (t < N_BUCKETS) bucket_base[t] = tile[t] - v;  // exclusive
  if (t == N_BUCKETS - 1) row_ptr[N_NODES] = tile[t];
}

// Pass B: one block per bucket; LDS-only atomics; col writes land in a ~16KB
// single-CU window.
__global__ __launch_bounds__(1024) void csr_build(
    const uint2* __restrict__ ebuf, const u64* __restrict__ bfill64,
    const int* __restrict__ bucket_base, int* __restrict__ row_ptr,
    float* __restrict__ inv_cnt, int* __restrict__ col) {
  __shared__ int hist[256];
  __shared__ int nscan[256];
  __shared__ int cursor[256];
  int b = blockIdx.x;
  int t = threadIdx.x;
  int nalloc = min((int)(bfill64[(size_t)b * 8] >> 32), EBUF_STRIDE);
  int bbase = bucket_base[b];
  if (t < 256) hist[t] = 0;
  __syncthreads();
  uint2 q[8];
#pragma unroll
  for (int k = 0; k < 8; k++) {
    int i = t + k * CSR_BLK;
    q[k].x = 0; q[k].y = SENT;
    if (i < nalloc) {
      q[k] = ebuf[(size_t)b * EBUF_STRIDE + i];
      if (q[k].y != SENT) atomicAdd(&hist[q[k].y & 255], 1);
    }
  }
  __syncthreads();
  if (t < 256) nscan[t] = hist[t];
  __syncthreads();
  for (int off = 1; off < 256; off <<= 1) {
    int add = 0;
    if (t < 256 && t >= off) add = nscan[t - off];
    __syncthreads();
    if (t < 256) nscan[t] += add;
    __syncthreads();
  }
  int nb = min(256, N_NODES - b * 256);
  if (t < 256) {
    int excl = nscan[t] - hist[t];
    cursor[t] = excl;
    if (t < nb) {
      row_ptr[b * 256 + t] = bbase + excl;
      inv_cnt[b * 256 + t] = 1.0f / fmaxf((float)hist[t], 1.0f);
    }
  }
  __syncthreads();
#pragma unroll
  for (int k = 0; k < 8; k++) {
    if (q[k].y != SENT) {
      int l = (int)(q[k].y & 255);
      int pos = bbase + atomicAdd(&cursor[l], 1);
      col[pos] = (int)q[k].x;
    }
  }
}

// ------------------------------------------------------------ converts ------
__global__ __launch_bounds__(256) void convert_x8(const float4* __restrict__ x,
                                                  unsigned* __restrict__ h8) {
  int i = blockIdx.x * blockDim.x + threadIdx.x;  // exactly N_NODES*64 threads
  float4 v = x[i];
  h8[i] = pack_fp8x4(v.x, v.y, v.z, v.w);
}

// Wt8[l][n][k] fp8: k<256 -> Wl[l][k][n], k>=256 -> Wr[l][k-256][n]
__global__ __launch_bounds__(256) void convert_w8(const float* __restrict__ Wl,
                                                  const float* __restrict__ Wr,
                                                  unsigned* __restrict__ Wt8) {
  int idx = blockIdx.x * blockDim.x + threadIdx.x;  // NLAYERS*512*HID/4 threads
  int l = idx >> 15;
  int r = idx & 32767;
  int n = r >> 7;
  int k4 = (r & 127) * 4;
  float v[4];
#pragma unroll
  for (int j = 0; j < 4; j++) {
    int k = k4 + j;
    v[j] = (k < 256) ? Wl[(size_t)l * 65536 + k * 256 + n]
                     : Wr[(size_t)l * 65536 + (k - 256) * 256 + n];
  }
  Wt8[idx] = pack_fp8x4(v[0], v[1], v[2], v[3]);
}

// ----------------------------------------------------------- aggregation ----
// one wave per node; two 32-lane halves process alternating edges with 8B fp8
// loads; at its empirical plateau (~6 TB/s logical) -- unchanged this round.
__global__ __launch_bounds__(256) void aggregate_fp8(
    const unsigned char* __restrict__ h8, const int* __restrict__ row_ptr,
    const int* __restrict__ col, const float* __restrict__ inv_cnt,
    unsigned char* __restrict__ aggr8) {
  int node = blockIdx.x * 4 + (threadIdx.x >> 6);
  int lane = threadIdx.x & 63;
  int half = lane >> 5, l32 = lane & 31;
  int r0 = row_ptr[node], r1 = row_ptr[node + 1];
  float a[8] = {0.f, 0.f, 0.f, 0.f, 0.f, 0.f, 0.f, 0.f};
  int e = r0 + half;
  for (; e + 14 < r1; e += 16) {
    int s[8];
#pragma unroll
    for (int j = 0; j < 8; j++) s[j] = col[e + 2 * j];
    uint2 v[8];
#pragma unroll
    for (int j = 0; j < 8; j++)
      v[j] = *((const uint2*)(h8 + (size_t)s[j] * HID) + l32);
#pragma unroll
    for (int j = 0; j < 8; j++) { accf8(a, v[j].x); accf8(a + 4, v[j].y); }
  }
  for (; e + 6 < r1; e += 8) {
    int s0 = col[e], s1 = col[e + 2], s2 = col[e + 4], s3 = col[e + 6];
    uint2 v0 = *((const uint2*)(h8 + (size_t)s0 * HID) + l32);
    uint2 v1 = *((const uint2*)(h8 + (size_t)s1 * HID) + l32);
    uint2 v2 = *((const uint2*)(h8 + (size_t)s2 * HID) + l32);
    uint2 v3 = *((const uint2*)(h8 + (size_t)s3 * HID) + l32);
    accf8(a, v0.x); accf8(a + 4, v0.y);
    accf8(a, v1.x); accf8(a + 4, v1.y);
    accf8(a, v2.x); accf8(a + 4, v2.y);
    accf8(a, v3.x); accf8(a + 4, v3.y);
  }
  for (; e < r1; e += 2) {
    int s0 = col[e];
    uint2 v0 = *((const uint2*)(h8 + (size_t)s0 * HID) + l32);
    accf8(a, v0.x); accf8(a + 4, v0.y);
  }
#pragma unroll
  for (int j = 0; j < 8; j++) a[j] += __shfl_xor(a[j], 32, 64);
  if (half == 0) {
    float inv = inv_cnt[node];
    uint2 o;
    o.x = pack_fp8x4(a[0] * inv, a[1] * inv, a[2] * inv, a[3] * inv);
    o.y = pack_fp8x4(a[4] * inv, a[5] * inv, a[6] * inv, a[7] * inv);
    *((uint2*)(aggr8 + (size_t)node * HID) + l32) = o;
  }
}

// ------------------------------- fp8 MFMA GEMM + fused BN partials ----------
// hpre8[m][n] = fp8(sum_k cat(aggr8,h8)[m][k] * B[k][n]);  B^T given as Wt8[n][k].
// 128x256 tile, BK=64 fp8, 2-PHASE DOUBLE-BUFFERED K-loop: STAGE(t+1) issued
// BEFORE ds_read+MFMA of tile t, ONE barrier per iteration -- the global_load_lds
// HBM latency (~900cy) hides under the 64-MFMA compute phase instead of being
// serialized by a vmcnt(0)-drain barrier right after issue (old structure).
__global__ __launch_bounds__(256, 2) void gemm_fused_fp8(
    const unsigned char* __restrict__ a8, const unsigned char* __restrict__ h8,
    const unsigned char* __restrict__ Bt8, unsigned char* __restrict__ hpre8,
    float* __restrict__ psum) {
  __shared__ unsigned char smem[2 * GEMM_BUF];  // 48 KB (2 x (A 8K + B 16K))
  __shared__ float bns[4][8][16][2];            // 4 KB

  int tid = threadIdx.x;
  int wid = tid >> 6, lane = tid & 63;
  int m0 = blockIdx.x * 128;
  int q = lane >> 4, c = lane & 15;
  int wm = (wid >> 1) * 64, wn = (wid & 1) * 128;

  f32x4 zero = {0.f, 0.f, 0.f, 0.f};
  f32x4 acc[4][8];
#pragma unroll
  for (int mi = 0; mi < 4; mi++)
#pragma unroll
    for (int ni = 0; ni < 8; ni++) acc[mi][ni] = zero;

  // A staging geometry (2 issues/thread); 16B chunk = 16 fp8 k-elems
  int srowA0 = wid * 32 + (lane >> 2);
  int cgA0 = (lane & 3) ^ ((srowA0 >> 1) & 3);
  int srowA1 = srowA0 + 16;
  int cgA1 = (lane & 3) ^ ((srowA1 >> 1) & 3);
  // B staging geometry (4 issues/thread)
  int srowB[4], cgB[4];
#pragma unroll
  for (int j = 0; j < 4; j++) {
    srowB[j] = j * 64 + wid * 16 + (lane >> 2);
    cgB[j] = (lane & 3) ^ ((srowB[j] >> 1) & 3);
  }

  // frag-read LDS byte offsets: per mi/ni and per kk (K=32 half of BK=64)
  int aoff[4][2], boff[8][2];
#pragma unroll
  for (int mi = 0; mi < 4; mi++) {
    int row = wm + mi * 16 + c;
    int x = (row >> 1) & 3;
#pragma unroll
    for (int kk = 0; kk < 2; kk++) {
      int chunk = kk * 2 + (q >> 1);
      aoff[mi][kk] = row * 64 + ((chunk ^ x) << 4) + ((q & 1) << 3);
    }
  }
#pragma unroll
  for (int ni = 0; ni < 8; ni++) {
    int row = wn + ni * 16 + c;
    int x = (row >> 1) & 3;
#pragma unroll
    for (int kk = 0; kk < 2; kk++) {
      int chunk = kk * 2 + (q >> 1);
      boff[ni][kk] = row * 64 + ((chunk ^ x) << 4) + ((q & 1) << 3);
    }
  }

  auto stage = [&](int k0, int b) {
    const unsigned char* Asrc = (k0 < 256) ? a8 : h8;
    int ksrc = k0 & 255;
    unsigned char* As = smem + b * GEMM_BUF;
    unsigned char* Bs = As + 128 * 64;
    gload16(Asrc + ((size_t)(m0 + srowA0) * HID + ksrc + cgA0 * 16),
            &As[(wid * 32) * 64]);
    gload16(Asrc + ((size_t)(m0 + srowA1) * HID + ksrc + cgA1 * 16),
            &As[(wid * 32 + 16) * 64]);
#pragma unroll
    for (int j = 0; j < 4; j++)
      gload16(Bt8 + ((size_t)srowB[j] * 512 + k0 + cgB[j] * 16),
              &Bs[(j * 64 + wid * 16) * 64]);
  };

  stage(0, 0);
  __syncthreads();  // drains vmcnt -> buf0 ready
#pragma unroll
  for (int t = 0; t < 8; ++t) {
    int cur = t & 1;
    if (t < 7) stage((t + 1) * 64, cur ^ 1);  // overlaps with ds_read + MFMA below
    const unsigned char* As = smem + cur * GEMM_BUF;
    const unsigned char* Bs = As + 128 * 64;
    long long af[4][2], bfr[8][2];
#pragma unroll
    for (int mi = 0; mi < 4; mi++) {
      af[mi][0] = *(const long long*)&As[aoff[mi][0]];
      af[mi][1] = *(const long long*)&As[aoff[mi][1]];
    }
#pragma unroll
    for (int ni = 0; ni < 8; ni++) {
      bfr[ni][0] = *(const long long*)&Bs[boff[ni][0]];
      bfr[ni][1] = *(const long long*)&Bs[boff[ni][1]];
    }
#pragma unroll
    for (int mi = 0; mi < 4; mi++)
#pragma unroll
      for (int ni = 0; ni < 8; ni++) {
        acc[mi][ni] = __builtin_amdgcn_mfma_f32_16x16x32_fp8_fp8(
            af[mi][0], bfr[ni][0], acc[mi][ni], 0, 0, 0);
        acc[mi][ni] = __builtin_amdgcn_mfma_f32_16x16x32_fp8_fp8(
            af[mi][1], bfr[ni][1], acc[mi][ni], 0, 0, 0);
      }
    __syncthreads();  // next tile staged (vmcnt drained) + buf[cur] reads done
  }

  // ---- coalesced fp8 C-store: 4 slabs of 32 rows via LDS transpose ----
  unsigned char* ep8 = smem;  // 32 x 256 fp8 = 8 KB
  int rh = wid >> 1;  // row half (0: rows 0-63, 1: rows 64-127)
#pragma unroll
  for (int mi = 0; mi < 4; mi++) {
#pragma unroll
    for (int r = 0; r < 4; r++) {
      int r16 = q * 4 + r;
#pragma unroll
      for (int ni = 0; ni < 8; ni++)
        ep8[(rh * 16 + r16) * 256 + wn + ni * 16 + c] = f2f8(acc[mi][ni][r]);
    }
    __syncthreads();
    int u = tid;
#pragma unroll
    for (int j = 0; j < 2; j++, u += 256) {  // 512 uint4 = 8 KB
      int lr = u >> 4;     // 0..31 local row
      int cu = u & 15;     // uint4 column (16 B = 16 cols)
      int gm = m0 + (lr >> 4) * 64 + mi * 16 + (lr & 15);
      if (gm < N_NODES)
        ((uint4*)(hpre8 + (size_t)gm * HID))[cu] = ((const uint4*)ep8)[u];
    }
    __syncthreads();
  }

  // ---- BN column partials from fp32 acc (mask pad rows) ----
#pragma unroll
  for (int ni = 0; ni < 8; ni++) {
    float s = 0.f, s2 = 0.f;
#pragma unroll
    for (int mi = 0; mi < 4; mi++) {
#pragma unroll
      for (int r = 0; r < 4; r++) {
        int gm = m0 + wm + mi * 16 + q * 4 + r;
        float v = (gm < N_NODES) ? acc[mi][ni][r] : 0.f;
        s += v;
        s2 += v * v;
      }
    }
    s += __shfl_xor(s, 16, 64);
    s += __shfl_xor(s, 32, 64);
    s2 += __shfl_xor(s2, 16, 64);
    s2 += __shfl_xor(s2, 32, 64);
    if (q == 0) {
      bns[wid][ni][c][0] = s;
      bns[wid][ni][c][1] = s2;
    }
  }
  __syncthreads();
  {
    int wnh = tid >> 7, ni = (tid >> 4) & 7, cc = tid & 15;
    float s = bns[wnh][ni][cc][0] + bns[wnh + 2][ni][cc][0];
    float s2 = bns[wnh][ni][cc][1] + bns[wnh + 2][ni][cc][1];
    int coln = wnh * 128 + ni * 16 + cc;
    psum[(size_t)blockIdx.x * 512 + coln] = s;
    psum[(size_t)blockIdx.x * 512 + 256 + coln] = s2;
  }
}

// --------------------------------- BN reduce (tree, atomic-free) ------------
#define BN_MID 16
__global__ __launch_bounds__(256) void bn_mid(const float* __restrict__ psum,
                                              float* __restrict__ tmp) {
  int b = blockIdx.x;
  int f = threadIdx.x;
  int mb0 = b * 49;
  int mb1 = min(mb0 + 49, N_MBLK);
  float s = 0.f, s2 = 0.f;
  for (int mb = mb0; mb < mb1; mb++) {
    s += psum[(size_t)mb * 512 + f];
    s2 += psum[(size_t)mb * 512 + 256 + f];
  }
  tmp[(size_t)b * 512 + f] = s;
  tmp[(size_t)b * 512 + 256 + f] = s2;
}

__global__ void bn_fin(const float* __restrict__ tmp,
                       const float* __restrict__ gamma,
                       const float* __restrict__ beta,
                       float* __restrict__ ss) {
  int f = threadIdx.x;
  float sum = 0.f, sq = 0.f;
#pragma unroll
  for (int b = 0; b < BN_MID; b++) {
    sum += tmp[(size_t)b * 512 + f];
    sq += tmp[(size_t)b * 512 + 256 + f];
  }
  const float invN = 1.0f / (float)N_NODES;
  float mu = sum * invN;
  float ex2 = sq * invN;
  float var = fmaxf(ex2 - mu * mu, 0.f);
  float sc = gamma[f] * rsqrtf(var + 1e-5f);
  ss[f] = sc;
  ss[HID + f] = beta[f] - mu * sc;
}

// BN+ReLU apply: fp8 hpre -> fp8 h (51 MB total traffic, was 77).
__global__ __launch_bounds__(256) void bn_apply_h8(const uint2* __restrict__ hpre8,
                                                   const float* __restrict__ ss,
                                                   uint2* __restrict__ h8out) {
  int idx0 = blockIdx.x * blockDim.x + threadIdx.x;
  int cb = (idx0 & 31) * 8;  // column base (row = 32 uint2)
  float sc[8], sh[8];
#pragma unroll
  for (int j = 0; j < 8; j++) { sc[j] = ss[cb + j]; sh[j] = ss[HID + cb + j]; }
  const int total = N_NODES * 32;
  const int step = gridDim.x * blockDim.x;  // 524288, multiple of 32
  for (int i = idx0; i < total; i += step) {
    uint2 v = hpre8[i];
    float f[8];
    decf8(f, v.x);
    decf8(f + 4, v.y);
#pragma unroll
    for (int j = 0; j < 8; j++)
      f[j] = fmaxf(fmaf(f[j], sc[j], sh[j]), 0.f);
    uint2 o;
    o.x = pack_fp8x4(f[0], f[1], f[2], f[3]);
    o.y = pack_fp8x4(f[4], f[5], f[6], f[7]);
    h8out[i] = o;
  }
}

// ---------------- pool stage 1: per-(graph, chunk) BN+ReLU partial sums -----
__global__ __launch_bounds__(256) void pool_partial(
    const unsigned char* __restrict__ hpre8, const float* __restrict__ ss,
    const int* __restrict__ batch, float* __restrict__ partial) {
  __shared__ float red[256][9];
  int g = blockIdx.x;
  int i = blockIdx.y;
  int t = threadIdx.x;
  int a = 0, b = N_NODES;
  while (a < b) { int m = (a + b) >> 1; if (batch[m] < g) a = m + 1; else b = m; }
  int lo = a;
  b = N_NODES;
  while (a < b) { int m = (a + b) >> 1; if (batch[m] < g + 1) a = m + 1; else b = m; }
  int hi = a;
  int len = hi - lo;
  int clen = (len + 7) >> 3;
  int c0 = lo + i * clen;
  int c1 = min(c0 + clen, hi);

  int rs = t >> 5, cu = t & 31;
  int cb = cu * 8;
  float scv[8], shv[8];
#pragma unroll
  for (int j = 0; j < 8; j++) { scv[j] = ss[cb + j]; shv[j] = ss[HID + cb + j]; }
  float acc[8] = {0.f, 0.f, 0.f, 0.f, 0.f, 0.f, 0.f, 0.f};
  for (int r = c0 + rs; r < c1; r += 8) {
    uint2 v = *((const uint2*)(hpre8 + (size_t)r * HID) + cu);
    float f[8];
    decf8(f, v.x);
    decf8(f + 4, v.y);
#pragma unroll
    for (int j = 0; j < 8; j++)
      acc[j] += fmaxf(fmaf(f[j], scv[j], shv[j]), 0.f);
  }
#pragma unroll
  for (int j = 0; j < 8; j++) red[t][j] = acc[j];
  __syncthreads();
  int cc = t >> 3, j = t & 7;
  float sum = 0.f;
#pragma unroll
  for (int k = 0; k < 8; k++) sum += red[k * 32 + cc][j];
  partial[((size_t)g * 8 + i) * 256 + t] = sum;
}

// ---------------- pool stage 2 + MLP (64 blocks, reads 8 partials/graph) ----
__global__ __launch_bounds__(256) void pool_mlp_final(
    const float* __restrict__ partial, const int* __restrict__ batch,
    const float* __restrict__ W1, const float* __restrict__ b1,
    const float* __restrict__ W2, const float* __restrict__ b2,
    float* __restrict__ out) {
  __shared__ float gs[HID];
  __shared__ float ts[HID];
  __shared__ float rn[PROJ];
  int g = blockIdx.x;
  int t = threadIdx.x;
  int a = 0, b = N_NODES;
  while (a < b) { int m = (a + b) >> 1; if (batch[m] < g) a = m + 1; else b = m; }
  int lo = a;
  b = N_NODES;
  while (a < b) { int m = (a + b) >> 1; if (batch[m] < g + 1) a = m + 1; else b = m; }
  int len = a - lo;

  float sum = 0.f;
#pragma unroll
  for (int i = 0; i < 8; i++) sum += partial[((size_t)g * 8 + i) * 256 + t];
  float inv = 1.0f / fmaxf((float)len, 1.0f);
  gs[t] = sum * inv;
  __syncthreads();

  float s = b1[t];
  for (int k = 0; k < HID; k++) s = fmaf(gs[k], W1[(size_t)k * HID + t], s);
  ts[t] = fmaxf(s, 0.f);
  __syncthreads();
  float z = 0.f;
  if (t < PROJ) {
    z = b2[t];
    for (int k = 0; k < HID; k++) z = fmaf(ts[k], W2[(size_t)k * PROJ + t], z);
    rn[t] = z * z;
  }
  __syncthreads();
  for (int off = PROJ / 2; off > 0; off >>= 1) {
    if (t < off) rn[t] += rn[t + off];
    __syncthreads();
  }
  float norm = fmaxf(sqrtf(rn[0]), 1e-12f);
  if (t < PROJ) out[(size_t)g * PROJ + t] = z / norm;
}

// --------------------------------------------------------------- launch -----
extern "C" void kernel_launch(void* const* d_in, const int* in_sizes, int n_in,
                              void* d_out, int out_size, void* d_ws, size_t ws_size,
                              hipStream_t stream) {
  const float* x = (const float*)d_in[0];
  const int* ei = (const int*)d_in[1];
  const int* src = ei;
  const int* dst = ei + N_EDGES;
  const int* batch = (const int*)d_in[2];
  const float* Wl = (const float*)d_in[3];
  // d_in[4] = bl: per-column bias is exactly cancelled by BatchNorm -> unused
  const float* Wr = (const float*)d_in[5];
  const float* gamma = (const float*)d_in[6];
  const float* beta = (const float*)d_in[7];
  const float* W1 = (const float*)d_in[8];
  const float* b1 = (const float*)d_in[9];
  const float* W2 = (const float*)d_in[10];
  const float* b2 = (const float*)d_in[11];
  float* out = (float*)d_out;

  char* p = (char*)d_ws;
  const size_t H8 = (size_t)M_PAD * HID;                 // 25.6 MB
  unsigned char* hpre8 = (unsigned char*)p; p += H8;     // fp8 pre-BN activations
  unsigned char* aggr8 = (unsigned char*)p; p += H8;
  unsigned char* h8 = (unsigned char*)p;    p += H8;
  unsigned char* Wt8 = (unsigned char*)p;   p += (size_t)NLAYERS * 512 * HID;  // 0.5 MB
  int* col = (int*)p;    p += (size_t)N_EDGES * sizeof(int);              // 6.4 MB
  int* row_ptr = (int*)p; p += 400016;
  float* inv_cnt = (float*)p; p += (size_t)N_NODES * sizeof(float);
  float* psum = (float*)p;    p += (size_t)N_MBLK * 512 * sizeof(float);  // 1.6 MB
  float* tmp = (float*)p;     p += (size_t)BN_MID * 512 * sizeof(float);
  float* ss = (float*)p;      p += 512 * sizeof(float);
  float* partial = (float*)p; p += (size_t)N_GRAPHS * 8 * 256 * sizeof(float);
  uint2* ebuf = (uint2*)p;    p += (size_t)N_BUCKETS * EBUF_STRIDE * sizeof(uint2);  // 25.6 MB

  // transient CSR-build arrays overlaid into hpre8 (first written in layer-0
  // gemm, which is stream-ordered after csr_build completes)
  u64* bfill64 = (u64*)hpre8;                      // N_BUCKETS lines (padded x8)
  int* bucket_base = (int*)(bfill64 + (size_t)N_BUCKETS * 8);

  // ---- build CSR (once; edge_index is layer-invariant) ----
  hipMemsetAsync(bfill64, 0, (size_t)N_BUCKETS * 8 * sizeof(u64), stream);
  bucket_scatter<<<CSR_NBLK, CSR_BLK, 0, stream>>>(src, dst, bfill64, ebuf);
  bucket_prefix<<<1, 512, 0, stream>>>(bfill64, bucket_base, row_ptr);
  csr_build<<<N_BUCKETS, CSR_BLK, 0, stream>>>(ebuf, bfill64, bucket_base,
                                               row_ptr, inv_cnt, col);

  // ---- one-time converts ----
  convert_x8<<<N_NODES / 4, 256, 0, stream>>>((const float4*)x, (unsigned*)h8);
  convert_w8<<<(NLAYERS * 512 * HID / 4) / 256, 256, 0, stream>>>(Wl, Wr,
                                                                  (unsigned*)Wt8);

  for (int l = 0; l < NLAYERS; l++) {
    aggregate_fp8<<<N_NODES / 4, 256, 0, stream>>>(h8, row_ptr, col, inv_cnt, aggr8);
    gemm_fused_fp8<<<N_MBLK, 256, 0, stream>>>(aggr8, h8,
                                               Wt8 + (size_t)l * 512 * HID,
                                               hpre8, psum);
    bn_mid<<<BN_MID, 256, 0, stream>>>(psum, tmp);
    bn_fin<<<1, 256, 0, stream>>>(tmp, gamma + (size_t)l * HID,
                                  beta + (size_t)l * HID, ss);
    if (l < NLAYERS - 1) {
      bn_apply_h8<<<2048, 256, 0, stream>>>((const uint2*)hpre8, ss, (uint2*)h8);
    }
  }

  // layer-3 BN+ReLU fused into two-stage pooling (reads hpre8 + ss)
  pool_partial<<<dim3(N_GRAPHS, 8), 256, 0, stream>>>(hpre8, ss, batch, partial);
  pool_mlp_final<<<N_GRAPHS, 256, 0, stream>>>(partial, batch, W1, b1, W2, b2, out);
}